// Round 4
// baseline (23875.281 us; speedup 1.0000x reference)
//
#include <hip/hip_runtime.h>
#include <hip/hip_bf16.h>

#define B_SZ 1024
#define T_SZ 128
#define D_SZ 256
#define H_SZ 512
#define NBLK 256
#define CBLK 16   // blocks per cluster (share one 64-row strip)

typedef __attribute__((ext_vector_type(8))) short short8;   // bf16x8 frag
typedef __attribute__((ext_vector_type(4))) float f32x4;    // f32 accum frag

__device__ inline void gll16(const void* g, void* l) {
  __builtin_amdgcn_global_load_lds(
      (const __attribute__((address_space(1))) unsigned int*)g,
      (__attribute__((address_space(3))) unsigned int*)l, 16, 0, 0);
}

__device__ inline f32x4 mfma16(short8 a, short8 b, f32x4 c) {
  return __builtin_amdgcn_mfma_f32_16x16x32_bf16(a, b, c, 0, 0, 0);
}

// Stage ROWSx64 bf16 tile into LDS [ROWS][64] ushort, slot-swizzled
// (slot s of row r holds global k-slot s^(r&7)); linear LDS dest for
// global_load_lds + inverse-swizzled SOURCE address (both-sides rule).
template <int ROWS>
__device__ inline void stageT(const __hip_bfloat16* __restrict__ src, int strideElts,
                              int row0, int k0, unsigned short* lds, int tid) {
  int wv = tid >> 6;
  constexpr int CH = ROWS * 8;  // 16B chunks
#pragma unroll
  for (int it = 0; it * 256 < CH; ++it) {
    int chunk = it * 256 + tid;
    int row = chunk >> 3, slot = chunk & 7;
    int ksrc = (slot ^ (row & 7)) << 3;
    const __hip_bfloat16* g = src + (size_t)(row0 + row) * strideElts + (k0 + ksrc);
    unsigned short* l = lds + (size_t)(it * 256 + (wv << 6)) * 8;  // wave-uniform base
    gll16((const void*)g, (void*)l);
  }
}

__device__ inline short8 ldfrag(const unsigned short* lds, int row, int slot) {
  int s = slot ^ (row & 7);
  return *(const short8*)(lds + row * 64 + s * 8);
}

#define TILE_SYNC()                                  \
  do {                                               \
    asm volatile("s_waitcnt vmcnt(0)" ::: "memory"); \
    __builtin_amdgcn_s_barrier();                    \
    __builtin_amdgcn_sched_barrier(0);               \
  } while (0)

// 16-way cluster barrier (sense-reversing, device-scope). Only CBLK blocks
// contend on this line; with the XCD swizzle they share one XCD's L2.
__device__ __forceinline__ void cbar(unsigned* cnt, unsigned* gen) {
  __syncthreads();
  if (threadIdx.x == 0) {
    __threadfence();  // release this block's stores (L2 writeback, device scope)
    unsigned g = __hip_atomic_load(gen, __ATOMIC_RELAXED, __HIP_MEMORY_SCOPE_AGENT);
    unsigned a = __hip_atomic_fetch_add(cnt, 1u, __ATOMIC_ACQ_REL, __HIP_MEMORY_SCOPE_AGENT);
    if (a == CBLK - 1) {
      __hip_atomic_store(cnt, 0u, __ATOMIC_RELAXED, __HIP_MEMORY_SCOPE_AGENT);
      __hip_atomic_fetch_add(gen, 1u, __ATOMIC_RELEASE, __HIP_MEMORY_SCOPE_AGENT);
    } else {
      while (__hip_atomic_load(gen, __ATOMIC_RELAXED, __HIP_MEMORY_SCOPE_AGENT) == g)
        __builtin_amdgcn_s_sleep(1);
    }
    __threadfence();  // acquire: invalidate stale cached lines before reads
  }
  __syncthreads();
}

__global__ __launch_bounds__(256, 2) void k_fused(
    const float* __restrict__ x, const float* __restrict__ xtime,
    const __hip_bfloat16* __restrict__ W1t, const float* __restrict__ b1,
    const __hip_bfloat16* __restrict__ W2t, const float* __restrict__ b2,
    const __hip_bfloat16* __restrict__ Wzrt, const float* __restrict__ bz,
    const float* __restrict__ br, const __hip_bfloat16* __restrict__ Wnt,
    const float* __restrict__ bn, float* __restrict__ hf, float* __restrict__ hstdf,
    float* __restrict__ hodef, float* __restrict__ zf,
    __hip_bfloat16* __restrict__ hbf, __hip_bfloat16* __restrict__ Ubf,
    __hip_bfloat16* __restrict__ hodeb, __hip_bfloat16* __restrict__ hstdb,
    __hip_bfloat16* __restrict__ A4, __hip_bfloat16* __restrict__ xstep,
    unsigned* __restrict__ bar) {
  __shared__ __align__(16) unsigned short lA[2][64 * 64];
  __shared__ __align__(16) unsigned short lB[2][64 * 64];
  int tid = threadIdx.x, lane = tid & 63, wv = tid >> 6;
  int lr = lane & 15, lg = lane >> 4;
  int b = blockIdx.x;
  // XCD-swizzle: round-robin dispatch puts blocks with equal (b&7) on one XCD;
  // group 16 such blocks into a cluster so its barrier+strip stay L2-local.
  // (Pure perf heuristic; correctness is device-scope regardless.)
  int xcd = b & 7, slot = b >> 3;          // slot 0..31
  int cl = (xcd << 1) | (slot >> 4);       // cluster 0..15
  int ci = slot & 15;                      // index within cluster 0..15
  int m0 = cl << 6;                        // 64-row strip base
  int n0a = ci << 5;                       // P1/P2 column slice (32 cols)
  int n0b = ci << 6;                       // P3/P4 column slice (64 cols)
  unsigned* cnt = bar + cl * 64;           // 256B per-cluster slot
  unsigned* gen = cnt + 32;                // separate 128B line

  for (int t = 0; t < T_SZ; ++t) {
    // ======== P1: U = tanh(h @ W1 + b1), cols [n0a, n0a+32) ========
    stageT<32>(W1t, H_SZ, n0a, 0, lB[0], tid);  // prestage B (sync-independent)
    cbar(cnt, gen);                              // wait prior step's h update
    {
      f32x4 acc[2] = {};
      stageT<64>(hbf, H_SZ, m0, 0, lA[0], tid);
      int cur = 0;
      for (int kt = 0; kt < 8; ++kt) {
        TILE_SYNC();
        if (kt + 1 < 8) {
          stageT<64>(hbf, H_SZ, m0, (kt + 1) << 6, lA[cur ^ 1], tid);
          stageT<32>(W1t, H_SZ, n0a, (kt + 1) << 6, lB[cur ^ 1], tid);
        }
#pragma unroll
        for (int kk = 0; kk < 2; ++kk) {
          short8 a = ldfrag(lA[cur], (wv << 4) + lr, (kk << 2) + lg);
#pragma unroll
          for (int n = 0; n < 2; ++n) {
            short8 bb = ldfrag(lB[cur], (n << 4) + lr, (kk << 2) + lg);
            acc[n] = mfma16(a, bb, acc[n]);
          }
        }
        cur ^= 1;
      }
#pragma unroll
      for (int n = 0; n < 2; ++n) {
        int col = n0a + (n << 4) + lr;
        float bi = b1[col];
        int r0 = m0 + (wv << 4) + (lg << 2);
#pragma unroll
        for (int r = 0; r < 4; ++r)
          Ubf[(size_t)(r0 + r) * H_SZ + col] = __float2bfloat16(tanhf(acc[n][r] + bi));
      }
    }
    // ======== P2: h_ode = h + dt*(U @ W2 + b2); x slice -> bf16 ========
    stageT<32>(W2t, H_SZ, n0a, 0, lB[0], tid);
    cbar(cnt, gen);
    {
      f32x4 acc[2] = {};
      stageT<64>(Ubf, H_SZ, m0, 0, lA[0], tid);
      int cur = 0;
      for (int kt = 0; kt < 8; ++kt) {
        TILE_SYNC();
        if (kt + 1 < 8) {
          stageT<64>(Ubf, H_SZ, m0, (kt + 1) << 6, lA[cur ^ 1], tid);
          stageT<32>(W2t, H_SZ, n0a, (kt + 1) << 6, lB[cur ^ 1], tid);
        }
#pragma unroll
        for (int kk = 0; kk < 2; ++kk) {
          short8 a = ldfrag(lA[cur], (wv << 4) + lr, (kk << 2) + lg);
#pragma unroll
          for (int n = 0; n < 2; ++n) {
            short8 bb = ldfrag(lB[cur], (n << 4) + lr, (kk << 2) + lg);
            acc[n] = mfma16(a, bb, acc[n]);
          }
        }
        cur ^= 1;
      }
      float dt = (t == 0) ? 0.01f : (xtime[t] - xtime[t - 1]);
#pragma unroll
      for (int n = 0; n < 2; ++n) {
        int col = n0a + (n << 4) + lr;
        float bi = b2[col];
        int r0 = m0 + (wv << 4) + (lg << 2);
#pragma unroll
        for (int r = 0; r < 4; ++r) {
          size_t ix = (size_t)(r0 + r) * H_SZ + col;
          float v = hf[ix] + dt * (acc[n][r] + bi);
          hodef[ix] = v;
          hodeb[ix] = __float2bfloat16(v);
        }
      }
      // x[:, t, :] -> bf16, 4 rows per block
      int xr = m0 + (ci << 2);
#pragma unroll
      for (int i = 0; i < 4; ++i) {
        float xv = x[((size_t)(xr + i) * T_SZ + t) * D_SZ + tid];
        xstep[(size_t)(xr + i) * D_SZ + tid] = __float2bfloat16(xv);
      }
    }
    // ======== P3: z|r = sigmoid(cat @ [Wz|Wr]); cols [n0b, n0b+64) ========
    stageT<64>(Wzrt, 1280, n0b, 0, lB[0], tid);
    cbar(cnt, gen);
    {
      f32x4 acc[4] = {};
      stageT<64>(hodeb, H_SZ, m0, 0, lA[0], tid);
      int cur = 0;
      for (int kt = 0; kt < 20; ++kt) {
        TILE_SYNC();
        if (kt + 1 < 20) {
          int ke = (kt + 1) << 6;
          if (ke < 512)       stageT<64>(hodeb, H_SZ, m0, ke, lA[cur ^ 1], tid);
          else if (ke < 1024) stageT<64>(hstdb, H_SZ, m0, ke - 512, lA[cur ^ 1], tid);
          else                stageT<64>(xstep, D_SZ, m0, ke - 1024, lA[cur ^ 1], tid);
          stageT<64>(Wzrt, 1280, n0b, ke, lB[cur ^ 1], tid);
        }
#pragma unroll
        for (int kk = 0; kk < 2; ++kk) {
          short8 a = ldfrag(lA[cur], (wv << 4) + lr, (kk << 2) + lg);
#pragma unroll
          for (int n = 0; n < 4; ++n) {
            short8 bb = ldfrag(lB[cur], (n << 4) + lr, (kk << 2) + lg);
            acc[n] = mfma16(a, bb, acc[n]);
          }
        }
        cur ^= 1;
      }
      int r0 = m0 + (wv << 4) + (lg << 2);
      if (ci < 8) {  // z columns
#pragma unroll
        for (int n = 0; n < 4; ++n) {
          int cg = n0b + (n << 4) + lr;
          float bi = bz[cg];
#pragma unroll
          for (int r = 0; r < 4; ++r) {
            float g = 1.f / (1.f + expf(-(acc[n][r] + bi)));
            zf[(size_t)(r0 + r) * H_SZ + cg] = g;
          }
        }
      } else {  // r columns -> build A4 = [h_ode*r | hstd*r]
#pragma unroll
        for (int n = 0; n < 4; ++n) {
          int j = n0b - 512 + (n << 4) + lr;
          float bi = br[j];
#pragma unroll
          for (int r = 0; r < 4; ++r) {
            int row = r0 + r;
            size_t ix = (size_t)row * H_SZ + j;
            float g = 1.f / (1.f + expf(-(acc[n][r] + bi)));
            A4[(size_t)row * 1024 + j]       = __float2bfloat16(hodef[ix] * g);
            A4[(size_t)row * 1024 + 512 + j] = __float2bfloat16(hstdf[ix] * g);
          }
        }
      }
    }
    // ======== P4: n = cat_r @ Wn + bn ; GRU update; cols [n0b, n0b+64) ========
    stageT<64>(Wnt, 1280, n0b, 0, lB[0], tid);
    cbar(cnt, gen);
    {
      f32x4 acc[4] = {};
      stageT<64>(A4, 1024, m0, 0, lA[0], tid);
      int cur = 0;
      for (int kt = 0; kt < 20; ++kt) {
        TILE_SYNC();
        if (kt + 1 < 20) {
          int ke = (kt + 1) << 6;
          if (ke < 1024) stageT<64>(A4, 1024, m0, ke, lA[cur ^ 1], tid);
          else           stageT<64>(xstep, D_SZ, m0, ke - 1024, lA[cur ^ 1], tid);
          stageT<64>(Wnt, 1280, n0b, ke, lB[cur ^ 1], tid);
        }
#pragma unroll
        for (int kk = 0; kk < 2; ++kk) {
          short8 a = ldfrag(lA[cur], (wv << 4) + lr, (kk << 2) + lg);
#pragma unroll
          for (int n = 0; n < 4; ++n) {
            short8 bb = ldfrag(lB[cur], (n << 4) + lr, (kk << 2) + lg);
            acc[n] = mfma16(a, bb, acc[n]);
          }
        }
        cur ^= 1;
      }
      int r0 = m0 + (wv << 4) + (lg << 2);
      if (ci < 8) {  // mean columns -> h update
#pragma unroll
        for (int n = 0; n < 4; ++n) {
          int c = n0b + (n << 4) + lr;
          float bi = bn[c];
#pragma unroll
          for (int r = 0; r < 4; ++r) {
            size_t ix = (size_t)(r0 + r) * H_SZ + c;
            float nm = acc[n][r] + bi;
            float z = zf[ix], ho = hodef[ix];
            float hn = (1.f - z) * nm + z * ho;
            hf[ix] = hn;
            hbf[ix] = __float2bfloat16(hn);
          }
        }
      } else {  // std columns -> hstd update
#pragma unroll
        for (int n = 0; n < 4; ++n) {
          int j = n0b - 512 + (n << 4) + lr;
          float bi = bn[512 + j];
#pragma unroll
          for (int r = 0; r < 4; ++r) {
            size_t ix = (size_t)(r0 + r) * H_SZ + j;
            float ns = fabsf(acc[n][r] + bi);
            float z = zf[ix], hs = hstdf[ix];
            float sn = fabsf((1.f - z) * ns + z * hs);
            hstdf[ix] = sn;
            hstdb[ix] = __float2bfloat16(sn);
          }
        }
      }
    }
  }
}

// =============== prep: W[k][n] f32  ->  Wt[n][k] bf16 =====================
__global__ void k_wt(const float* __restrict__ W, __hip_bfloat16* __restrict__ Wt,
                     int K, int N, int ld) {
  size_t i = (size_t)blockIdx.x * 256 + threadIdx.x;
  if (i >= (size_t)K * N) return;
  int n = (int)(i / K), k = (int)(i % K);
  Wt[(size_t)n * ld + k] = __float2bfloat16(W[(size_t)k * N + n]);
}

extern "C" void kernel_launch(void* const* d_in, const int* in_sizes, int n_in,
                              void* d_out, int out_size, void* d_ws, size_t ws_size,
                              hipStream_t stream) {
  const float* x     = (const float*)d_in[0];
  const float* xtime = (const float*)d_in[1];
  const float* W1    = (const float*)d_in[2];
  const float* b1    = (const float*)d_in[3];
  const float* W2    = (const float*)d_in[4];
  const float* b2    = (const float*)d_in[5];
  const float* Wz    = (const float*)d_in[6];
  const float* bz    = (const float*)d_in[7];
  const float* Wr    = (const float*)d_in[8];
  const float* br    = (const float*)d_in[9];
  const float* Wn    = (const float*)d_in[10];
  const float* bn    = (const float*)d_in[11];

  char* p = (char*)d_ws;
  __hip_bfloat16* W1t   = (__hip_bfloat16*)(p + 0);         //  512x512
  __hip_bfloat16* W2t   = (__hip_bfloat16*)(p + 524288);    //  512x512
  __hip_bfloat16* Wzrt  = (__hip_bfloat16*)(p + 1048576);   // 1024x1280
  __hip_bfloat16* Wnt   = (__hip_bfloat16*)(p + 3670016);   // 1024x1280
  float*          hf    = (float*)(p + 6291456);            // 1024x512 state
  float*          hstdf = (float*)(p + 8388608);            // 1024x512 state
  float*          hodef = (float*)(p + 10485760);
  float*          zf    = (float*)(p + 12582912);
  __hip_bfloat16* hbf   = (__hip_bfloat16*)(p + 14680064);
  __hip_bfloat16* Ubf   = (__hip_bfloat16*)(p + 15728640);
  __hip_bfloat16* hodeb = (__hip_bfloat16*)(p + 16777216);
  __hip_bfloat16* hstdb = (__hip_bfloat16*)(p + 17825792);
  __hip_bfloat16* A4    = (__hip_bfloat16*)(p + 18874368);  // 1024x1024
  __hip_bfloat16* xstep = (__hip_bfloat16*)(p + 20971520);  // 1024x256
  unsigned*       bar   = (unsigned*)(p + 21495808);        // 16 x 256B cluster slots

  // zero recurrent state + barriers (harness does not re-poison between replays)
  hipMemsetAsync(hf, 0, 2097152, stream);
  hipMemsetAsync(hstdf, 0, 2097152, stream);
  hipMemsetAsync(hbf, 0, 1048576, stream);
  hipMemsetAsync(hstdb, 0, 1048576, stream);
  hipMemsetAsync(bar, 0, 4096, stream);

  // weights -> bf16, transposed to [N][K]
  k_wt<<<(512 * 512 + 255) / 256, 256, 0, stream>>>(W1, W1t, 512, 512, 512);
  k_wt<<<(512 * 512 + 255) / 256, 256, 0, stream>>>(W2, W2t, 512, 512, 512);
  k_wt<<<(1280 * 512 + 255) / 256, 256, 0, stream>>>(Wz, Wzrt, 1280, 512, 1280);
  k_wt<<<(1280 * 512 + 255) / 256, 256, 0, stream>>>(Wr, Wzrt + (size_t)512 * 1280, 1280, 512, 1280);
  k_wt<<<(1280 * 1024 + 255) / 256, 256, 0, stream>>>(Wn, Wnt, 1280, 1024, 1280);

  // one persistent kernel, 16 clusters x 16 blocks, cluster-local syncs only
  k_fused<<<NBLK, 256, 0, stream>>>(x, xtime, W1t, b1, W2t, b2, Wzrt, bz, br,
                                    Wnt, bn, hf, hstdf, hodef, zf, hbf, Ubf,
                                    hodeb, hstdb, A4, xstep, bar);

  hipMemcpyAsync(d_out, hf, 2097152, hipMemcpyDeviceToDevice, stream);
  hipMemcpyAsync((char*)d_out + 2097152, hstdf, 2097152, hipMemcpyDeviceToDevice, stream);
}

// Round 5
// 13731.607 us; speedup vs baseline: 1.7387x; 1.7387x over previous
//
#include <hip/hip_runtime.h>
#include <hip/hip_bf16.h>

#define B_SZ 1024
#define T_SZ 128
#define D_SZ 256
#define H_SZ 512
#define NBLK 256
#define CBLK 16     // blocks per cluster (share one 64-row strip)
#define AUXS 0x11   // CPol: SC0|SC1 -> system-coherent, bypass L1/L2 (state)

typedef __attribute__((ext_vector_type(8))) short short8;   // bf16x8 frag
typedef __attribute__((ext_vector_type(4))) float f32x4;    // f32 accum frag

__device__ inline f32x4 mfma16(short8 a, short8 b, f32x4 c) {
  return __builtin_amdgcn_mfma_f32_16x16x32_bf16(a, b, c, 0, 0, 0);
}

// ---- system-coherent scalar stores (write-through to L3, no stale L2) ----
__device__ inline void st_sys_f32(float* p, float v) {
  asm volatile("global_store_dword %0, %1, off sc0 sc1" :: "v"(p), "v"(v) : "memory");
}
__device__ inline void st_sys_bf16(__hip_bfloat16* p, float v) {
  union { __hip_bfloat16 b; unsigned short u; } cv;
  cv.b = __float2bfloat16(v);
  unsigned int vv = cv.u;
  asm volatile("global_store_short %0, %1, off sc0 sc1" :: "v"(p), "v"(vv) : "memory");
}

// Stage ROWSx64 bf16 tile into LDS [ROWS][64] ushort, slot-swizzled
// (slot s of row r holds global k-slot s^(r&7)); linear LDS dest for
// global_load_lds + inverse-swizzled SOURCE address (both-sides rule).
// AUX=0: normal cached (weights). AUX=AUXS: system-coherent (state).
template <int ROWS, int AUX>
__device__ inline void stageT(const __hip_bfloat16* __restrict__ src, int strideElts,
                              int row0, int k0, unsigned short* lds, int tid) {
  constexpr int CH = ROWS * 8;  // 16B chunks
#pragma unroll
  for (int it = 0; it * 256 < CH; ++it) {
    int chunk = it * 256 + tid;
    int row = chunk >> 3, slot = chunk & 7;
    int ksrc = (slot ^ (row & 7)) << 3;
    const __hip_bfloat16* g = src + (size_t)(row0 + row) * strideElts + (k0 + ksrc);
    unsigned short* l = lds + (size_t)(it * 256 + ((tid >> 6) << 6)) * 8;
    __builtin_amdgcn_global_load_lds(
        (const __attribute__((address_space(1))) unsigned int*)g,
        (__attribute__((address_space(3))) unsigned int*)l, 16, 0, AUX);
  }
}

// Stage ROWSxCOLS f32 tile into LDS (linear row-major), system-coherent.
template <int ROWS, int COLS>
__device__ inline void stageF(const float* __restrict__ src, int strideElts,
                              int row0, int col0, float* lds, int tid) {
  constexpr int CH = ROWS * COLS / 4;  // 16B chunks
#pragma unroll
  for (int it = 0; it * 256 < CH; ++it) {
    int chunk = it * 256 + tid;
    int row = chunk / (COLS / 4), cs = chunk % (COLS / 4);
    const float* g = src + (size_t)(row0 + row) * strideElts + col0 + cs * 4;
    float* l = lds + (size_t)(it * 256 + ((tid >> 6) << 6)) * 4;
    __builtin_amdgcn_global_load_lds(
        (const __attribute__((address_space(1))) unsigned int*)g,
        (__attribute__((address_space(3))) unsigned int*)l, 16, 0, AUXS);
  }
}

__device__ inline short8 ldfrag(const unsigned short* lds, int row, int slot) {
  int s = slot ^ (row & 7);
  return *(const short8*)(lds + row * 64 + s * 8);
}

#define TILE_SYNC()                                  \
  do {                                               \
    asm volatile("s_waitcnt vmcnt(0)" ::: "memory"); \
    __builtin_amdgcn_s_barrier();                    \
    __builtin_amdgcn_sched_barrier(0);               \
  } while (0)

// Cluster barrier with NO cache-maintenance ops (keeps L2 weight-hot).
// State visibility comes from sc0/sc1 data path, not fences. Every wave
// drains its sc-stores (vmcnt) before the block signals arrival.
__device__ __forceinline__ void cbar(unsigned* cnt, unsigned* gen) {
  asm volatile("s_waitcnt vmcnt(0)" ::: "memory");  // ALL waves drain stores
  __syncthreads();
  if (threadIdx.x == 0) {
    unsigned g = __hip_atomic_load(gen, __ATOMIC_RELAXED, __HIP_MEMORY_SCOPE_AGENT);
    unsigned a = __hip_atomic_fetch_add(cnt, 1u, __ATOMIC_RELAXED, __HIP_MEMORY_SCOPE_AGENT);
    if (a == CBLK - 1) {
      __hip_atomic_store(cnt, 0u, __ATOMIC_RELAXED, __HIP_MEMORY_SCOPE_AGENT);
      asm volatile("s_waitcnt vmcnt(0)" ::: "memory");  // cnt reset visible first
      __hip_atomic_store(gen, g + 1u, __ATOMIC_RELAXED, __HIP_MEMORY_SCOPE_AGENT);
    } else {
      while (__hip_atomic_load(gen, __ATOMIC_RELAXED, __HIP_MEMORY_SCOPE_AGENT) == g)
        __builtin_amdgcn_s_sleep(2);
    }
  }
  __syncthreads();
  __builtin_amdgcn_sched_barrier(0);
}

__global__ __launch_bounds__(256, 2) void k_fused(
    const float* __restrict__ x, const float* __restrict__ xtime,
    const __hip_bfloat16* __restrict__ W1t, const float* __restrict__ b1,
    const __hip_bfloat16* __restrict__ W2t, const float* __restrict__ b2,
    const __hip_bfloat16* __restrict__ Wzrt, const float* __restrict__ bz,
    const float* __restrict__ br, const __hip_bfloat16* __restrict__ Wnt,
    const float* __restrict__ bn, float* __restrict__ hf, float* __restrict__ hstdf,
    float* __restrict__ hodef, float* __restrict__ zf,
    __hip_bfloat16* __restrict__ hbf, __hip_bfloat16* __restrict__ Ubf,
    __hip_bfloat16* __restrict__ hodeb, __hip_bfloat16* __restrict__ hstdb,
    __hip_bfloat16* __restrict__ A4, __hip_bfloat16* __restrict__ xstep,
    unsigned* __restrict__ bar) {
  __shared__ __align__(16) unsigned short lA[2][64 * 64];
  __shared__ __align__(16) unsigned short lB[2][64 * 64];
  __shared__ __align__(16) float lS0[64 * 64];
  __shared__ __align__(16) float lS1[64 * 64];
  int tid = threadIdx.x, lane = tid & 63, wv = tid >> 6;
  int lr = lane & 15, lg = lane >> 4;
  int b = blockIdx.x;
  int xcd = b & 7, slot = b >> 3;          // round-robin XCD heuristic
  int cl = (xcd << 1) | (slot >> 4);       // cluster 0..15
  int ci = slot & 15;                      // index within cluster 0..15
  int m0 = cl << 6;                        // 64-row strip base
  int n0a = ci << 5;                       // P1/P2 column slice (32 cols)
  int n0b = ci << 6;                       // P3/P4 column slice (64 cols)
  unsigned* cnt = bar + cl * 64;
  unsigned* gen = cnt + 32;

  for (int t = 0; t < T_SZ; ++t) {
    // ======== P1: U = tanh(h @ W1 + b1), cols [n0a, n0a+32) ========
    stageT<32, 0>(W1t, H_SZ, n0a, 0, lB[0], tid);  // weights: cached, pre-barrier
    cbar(cnt, gen);                                 // wait prior step's h
    {
      f32x4 acc[2] = {};
      stageT<64, AUXS>(hbf, H_SZ, m0, 0, lA[0], tid);
      int cur = 0;
      for (int kt = 0; kt < 8; ++kt) {
        TILE_SYNC();
        if (kt + 1 < 8) {
          stageT<64, AUXS>(hbf, H_SZ, m0, (kt + 1) << 6, lA[cur ^ 1], tid);
          stageT<32, 0>(W1t, H_SZ, n0a, (kt + 1) << 6, lB[cur ^ 1], tid);
        }
#pragma unroll
        for (int kk = 0; kk < 2; ++kk) {
          short8 a = ldfrag(lA[cur], (wv << 4) + lr, (kk << 2) + lg);
#pragma unroll
          for (int n = 0; n < 2; ++n) {
            short8 bb = ldfrag(lB[cur], (n << 4) + lr, (kk << 2) + lg);
            acc[n] = mfma16(a, bb, acc[n]);
          }
        }
        cur ^= 1;
      }
#pragma unroll
      for (int n = 0; n < 2; ++n) {
        int col = n0a + (n << 4) + lr;
        float bi = b1[col];
        int r0 = m0 + (wv << 4) + (lg << 2);
#pragma unroll
        for (int r = 0; r < 4; ++r)
          st_sys_bf16(&Ubf[(size_t)(r0 + r) * H_SZ + col], tanhf(acc[n][r] + bi));
      }
    }
    // ======== P2: h_ode = h + dt*(U @ W2 + b2); x slice -> bf16 ========
    stageT<32, 0>(W2t, H_SZ, n0a, 0, lB[0], tid);
    cbar(cnt, gen);
    stageF<64, 32>(hf, H_SZ, m0, n0a, lS0, tid);  // f32 h tile for epilogue
    {
      f32x4 acc[2] = {};
      stageT<64, AUXS>(Ubf, H_SZ, m0, 0, lA[0], tid);
      int cur = 0;
      for (int kt = 0; kt < 8; ++kt) {
        TILE_SYNC();
        if (kt + 1 < 8) {
          stageT<64, AUXS>(Ubf, H_SZ, m0, (kt + 1) << 6, lA[cur ^ 1], tid);
          stageT<32, 0>(W2t, H_SZ, n0a, (kt + 1) << 6, lB[cur ^ 1], tid);
        }
#pragma unroll
        for (int kk = 0; kk < 2; ++kk) {
          short8 a = ldfrag(lA[cur], (wv << 4) + lr, (kk << 2) + lg);
#pragma unroll
          for (int n = 0; n < 2; ++n) {
            short8 bb = ldfrag(lB[cur], (n << 4) + lr, (kk << 2) + lg);
            acc[n] = mfma16(a, bb, acc[n]);
          }
        }
        cur ^= 1;
      }
      float dt = (t == 0) ? 0.01f : (xtime[t] - xtime[t - 1]);
#pragma unroll
      for (int n = 0; n < 2; ++n) {
        int col = n0a + (n << 4) + lr;
        float bi = b2[col];
        int r0 = m0 + (wv << 4) + (lg << 2);
#pragma unroll
        for (int r = 0; r < 4; ++r) {
          int rl = (wv << 4) + (lg << 2) + r;
          float v = lS0[rl * 32 + (n << 4) + lr] + dt * (acc[n][r] + bi);
          size_t ix = (size_t)(r0 + r) * H_SZ + col;
          st_sys_f32(&hodef[ix], v);
          st_sys_bf16(&hodeb[ix], v);
        }
      }
      int xr = m0 + (ci << 2);  // x[:, t, :] -> bf16, 4 rows per block
#pragma unroll
      for (int i = 0; i < 4; ++i) {
        float xv = x[((size_t)(xr + i) * T_SZ + t) * D_SZ + tid];
        st_sys_bf16(&xstep[(size_t)(xr + i) * D_SZ + tid], xv);
      }
    }
    // ======== P3: z|r = sigmoid(cat @ [Wz|Wr]); cols [n0b, n0b+64) ========
    stageT<64, 0>(Wzrt, 1280, n0b, 0, lB[0], tid);
    cbar(cnt, gen);
    if (ci >= 8) {  // r-blocks need f32 h_ode, hstd tiles for A4 build
      stageF<64, 64>(hodef, H_SZ, m0, n0b - 512, lS0, tid);
      stageF<64, 64>(hstdf, H_SZ, m0, n0b - 512, lS1, tid);
    }
    {
      f32x4 acc[4] = {};
      stageT<64, AUXS>(hodeb, H_SZ, m0, 0, lA[0], tid);
      int cur = 0;
      for (int kt = 0; kt < 20; ++kt) {
        TILE_SYNC();
        if (kt + 1 < 20) {
          int ke = (kt + 1) << 6;
          if (ke < 512)       stageT<64, AUXS>(hodeb, H_SZ, m0, ke, lA[cur ^ 1], tid);
          else if (ke < 1024) stageT<64, AUXS>(hstdb, H_SZ, m0, ke - 512, lA[cur ^ 1], tid);
          else                stageT<64, AUXS>(xstep, D_SZ, m0, ke - 1024, lA[cur ^ 1], tid);
          stageT<64, 0>(Wzrt, 1280, n0b, ke, lB[cur ^ 1], tid);
        }
#pragma unroll
        for (int kk = 0; kk < 2; ++kk) {
          short8 a = ldfrag(lA[cur], (wv << 4) + lr, (kk << 2) + lg);
#pragma unroll
          for (int n = 0; n < 4; ++n) {
            short8 bb = ldfrag(lB[cur], (n << 4) + lr, (kk << 2) + lg);
            acc[n] = mfma16(a, bb, acc[n]);
          }
        }
        cur ^= 1;
      }
      int r0 = m0 + (wv << 4) + (lg << 2);
      if (ci < 8) {  // z columns
#pragma unroll
        for (int n = 0; n < 4; ++n) {
          int cg = n0b + (n << 4) + lr;
          float bi = bz[cg];
#pragma unroll
          for (int r = 0; r < 4; ++r) {
            float g = 1.f / (1.f + expf(-(acc[n][r] + bi)));
            st_sys_f32(&zf[(size_t)(r0 + r) * H_SZ + cg], g);
          }
        }
      } else {  // r columns -> A4 = [h_ode*r | hstd*r]
#pragma unroll
        for (int n = 0; n < 4; ++n) {
          int j = n0b - 512 + (n << 4) + lr;
          float bi = br[j];
#pragma unroll
          for (int r = 0; r < 4; ++r) {
            int row = r0 + r;
            int rl = (wv << 4) + (lg << 2) + r, clc = (n << 4) + lr;
            float g = 1.f / (1.f + expf(-(acc[n][r] + bi)));
            st_sys_bf16(&A4[(size_t)row * 1024 + j], lS0[rl * 64 + clc] * g);
            st_sys_bf16(&A4[(size_t)row * 1024 + 512 + j], lS1[rl * 64 + clc] * g);
          }
        }
      }
    }
    // ======== P4: n = cat_r @ Wn + bn ; GRU update; cols [n0b, n0b+64) ========
    stageT<64, 0>(Wnt, 1280, n0b, 0, lB[0], tid);
    cbar(cnt, gen);
    if (ci < 8) {  // mean-blocks: zf + h_ode tiles
      stageF<64, 64>(zf, H_SZ, m0, n0b, lS0, tid);
      stageF<64, 64>(hodef, H_SZ, m0, n0b, lS1, tid);
    } else {       // std-blocks: zf + hstd tiles
      stageF<64, 64>(zf, H_SZ, m0, n0b - 512, lS0, tid);
      stageF<64, 64>(hstdf, H_SZ, m0, n0b - 512, lS1, tid);
    }
    {
      f32x4 acc[4] = {};
      stageT<64, AUXS>(A4, 1024, m0, 0, lA[0], tid);
      int cur = 0;
      for (int kt = 0; kt < 20; ++kt) {
        TILE_SYNC();
        if (kt + 1 < 20) {
          int ke = (kt + 1) << 6;
          if (ke < 1024) stageT<64, AUXS>(A4, 1024, m0, ke, lA[cur ^ 1], tid);
          else           stageT<64, AUXS>(xstep, D_SZ, m0, ke - 1024, lA[cur ^ 1], tid);
          stageT<64, 0>(Wnt, 1280, n0b, ke, lB[cur ^ 1], tid);
        }
#pragma unroll
        for (int kk = 0; kk < 2; ++kk) {
          short8 a = ldfrag(lA[cur], (wv << 4) + lr, (kk << 2) + lg);
#pragma unroll
          for (int n = 0; n < 4; ++n) {
            short8 bb = ldfrag(lB[cur], (n << 4) + lr, (kk << 2) + lg);
            acc[n] = mfma16(a, bb, acc[n]);
          }
        }
        cur ^= 1;
      }
      int r0 = m0 + (wv << 4) + (lg << 2);
      if (ci < 8) {  // mean columns -> h update
#pragma unroll
        for (int n = 0; n < 4; ++n) {
          int c = n0b + (n << 4) + lr;
          float bi = bn[c];
#pragma unroll
          for (int r = 0; r < 4; ++r) {
            int rl = (wv << 4) + (lg << 2) + r, clc = (n << 4) + lr;
            size_t ix = (size_t)(r0 + r) * H_SZ + c;
            float nm = acc[n][r] + bi;
            float z = lS0[rl * 64 + clc], ho = lS1[rl * 64 + clc];
            float hn = (1.f - z) * nm + z * ho;
            st_sys_f32(&hf[ix], hn);
            st_sys_bf16(&hbf[ix], hn);
          }
        }
      } else {  // std columns -> hstd update
#pragma unroll
        for (int n = 0; n < 4; ++n) {
          int j = n0b - 512 + (n << 4) + lr;
          float bi = bn[512 + j];
#pragma unroll
          for (int r = 0; r < 4; ++r) {
            int rl = (wv << 4) + (lg << 2) + r, clc = (n << 4) + lr;
            size_t ix = (size_t)(r0 + r) * H_SZ + j;
            float ns = fabsf(acc[n][r] + bi);
            float z = lS0[rl * 64 + clc], hs = lS1[rl * 64 + clc];
            float sn = fabsf((1.f - z) * ns + z * hs);
            st_sys_f32(&hstdf[ix], sn);
            st_sys_bf16(&hstdb[ix], sn);
          }
        }
      }
    }
  }
}

// =============== prep: W[k][n] f32  ->  Wt[n][k] bf16 =====================
__global__ void k_wt(const float* __restrict__ W, __hip_bfloat16* __restrict__ Wt,
                     int K, int N, int ld) {
  size_t i = (size_t)blockIdx.x * 256 + threadIdx.x;
  if (i >= (size_t)K * N) return;
  int n = (int)(i / K), k = (int)(i % K);
  Wt[(size_t)n * ld + k] = __float2bfloat16(W[(size_t)k * N + n]);
}

extern "C" void kernel_launch(void* const* d_in, const int* in_sizes, int n_in,
                              void* d_out, int out_size, void* d_ws, size_t ws_size,
                              hipStream_t stream) {
  const float* x     = (const float*)d_in[0];
  const float* xtime = (const float*)d_in[1];
  const float* W1    = (const float*)d_in[2];
  const float* b1    = (const float*)d_in[3];
  const float* W2    = (const float*)d_in[4];
  const float* b2    = (const float*)d_in[5];
  const float* Wz    = (const float*)d_in[6];
  const float* bz    = (const float*)d_in[7];
  const float* Wr    = (const float*)d_in[8];
  const float* br    = (const float*)d_in[9];
  const float* Wn    = (const float*)d_in[10];
  const float* bn    = (const float*)d_in[11];

  char* p = (char*)d_ws;
  __hip_bfloat16* W1t   = (__hip_bfloat16*)(p + 0);         //  512x512
  __hip_bfloat16* W2t   = (__hip_bfloat16*)(p + 524288);    //  512x512
  __hip_bfloat16* Wzrt  = (__hip_bfloat16*)(p + 1048576);   // 1024x1280
  __hip_bfloat16* Wnt   = (__hip_bfloat16*)(p + 3670016);   // 1024x1280
  float*          hf    = (float*)(p + 6291456);            // 1024x512 state
  float*          hstdf = (float*)(p + 8388608);            // 1024x512 state
  float*          hodef = (float*)(p + 10485760);
  float*          zf    = (float*)(p + 12582912);
  __hip_bfloat16* hbf   = (__hip_bfloat16*)(p + 14680064);
  __hip_bfloat16* Ubf   = (__hip_bfloat16*)(p + 15728640);
  __hip_bfloat16* hodeb = (__hip_bfloat16*)(p + 16777216);
  __hip_bfloat16* hstdb = (__hip_bfloat16*)(p + 17825792);
  __hip_bfloat16* A4    = (__hip_bfloat16*)(p + 18874368);  // 1024x1024
  __hip_bfloat16* xstep = (__hip_bfloat16*)(p + 20971520);  // 1024x256
  unsigned*       bar   = (unsigned*)(p + 21495808);        // 16 x 256B cluster slots

  // zero recurrent state + barriers (flushed to memory at kernel boundary,
  // so the kernel's sc0/sc1 loads see them)
  hipMemsetAsync(hf, 0, 2097152, stream);
  hipMemsetAsync(hstdf, 0, 2097152, stream);
  hipMemsetAsync(hbf, 0, 1048576, stream);
  hipMemsetAsync(hstdb, 0, 1048576, stream);
  hipMemsetAsync(bar, 0, 4096, stream);

  // weights -> bf16, transposed to [N][K]
  k_wt<<<(512 * 512 + 255) / 256, 256, 0, stream>>>(W1, W1t, 512, 512, 512);
  k_wt<<<(512 * 512 + 255) / 256, 256, 0, stream>>>(W2, W2t, 512, 512, 512);
  k_wt<<<(1280 * 512 + 255) / 256, 256, 0, stream>>>(Wz, Wzrt, 1280, 512, 1280);
  k_wt<<<(1280 * 512 + 255) / 256, 256, 0, stream>>>(Wr, Wzrt + (size_t)512 * 1280, 1280, 512, 1280);
  k_wt<<<(1280 * 1024 + 255) / 256, 256, 0, stream>>>(Wn, Wnt, 1280, 1024, 1280);

  // one persistent kernel, 16 clusters x 16 blocks; weights cached in L2
  // (no cache-maintenance ops anywhere), state exchanged via sc0/sc1 path
  k_fused<<<NBLK, 256, 0, stream>>>(x, xtime, W1t, b1, W2t, b2, Wzrt, bz, br,
                                    Wnt, bn, hf, hstdf, hodef, zf, hbf, Ubf,
                                    hodeb, hstdb, A4, xstep, bar);

  hipMemcpyAsync(d_out, hf, 2097152, hipMemcpyDeviceToDevice, stream);
  hipMemcpyAsync((char*)d_out + 2097152, hstdf, 2097152, hipMemcpyDeviceToDevice, stream);
}

// Round 6
// 8119.269 us; speedup vs baseline: 2.9406x; 1.6912x over previous
//
#include <hip/hip_runtime.h>
#include <hip/hip_bf16.h>

#define B_SZ 1024
#define T_SZ 128
#define D_SZ 256
#define H_SZ 512
#define NBLK 256
#define AUXS 0x11   // CPol SC0|SC1: system-coherent, bypass L1/L2 (state path)

typedef __attribute__((ext_vector_type(8))) short short8;
typedef __attribute__((ext_vector_type(4))) float f32x4;

__device__ inline f32x4 mfma16(short8 a, short8 b, f32x4 c) {
  return __builtin_amdgcn_mfma_f32_16x16x32_bf16(a, b, c, 0, 0, 0);
}

__device__ inline void st_sys_f32(float* p, float v) {
  asm volatile("global_store_dword %0, %1, off sc0 sc1" :: "v"(p), "v"(v) : "memory");
}
__device__ inline void st_sys_bf16(__hip_bfloat16* p, float v) {
  union { __hip_bfloat16 b; unsigned short u; } cv;
  cv.b = __float2bfloat16(v);
  unsigned int vv = cv.u;
  asm volatile("global_store_short %0, %1, off sc0 sc1" :: "v"(p), "v"(vv) : "memory");
}

// Stage ROWSx64 bf16 tile -> LDS [ROWS][64], slot-swizzled (slot s of row r
// holds k-slot s^(r&7)); linear LDS dest + inverse-swizzled global source.
template <int ROWS, int AUX>
__device__ __forceinline__ void stageT(const __hip_bfloat16* __restrict__ src,
                                       int strideElts, int row0, int k0,
                                       unsigned short* lds, int tid) {
  constexpr int CH = ROWS * 8;
#pragma unroll
  for (int it = 0; it * 256 < CH; ++it) {
    int chunk = it * 256 + tid;
    int row = chunk >> 3, slot = chunk & 7;
    int ksrc = (slot ^ (row & 7)) << 3;
    const __hip_bfloat16* g = src + (size_t)(row0 + row) * strideElts + (k0 + ksrc);
    unsigned short* l = lds + (size_t)(it * 256 + ((tid >> 6) << 6)) * 8;
    __builtin_amdgcn_global_load_lds(
        (const __attribute__((address_space(1))) unsigned int*)g,
        (__attribute__((address_space(3))) unsigned int*)l, 16, 0, AUX);
  }
}

// Stage ROWSxCOLS f32 tile -> LDS linear row-major, system-coherent.
template <int ROWS, int COLS>
__device__ __forceinline__ void stageF(const float* __restrict__ src, int strideElts,
                                       int row0, int col0, float* lds, int tid) {
  constexpr int CH = ROWS * COLS / 4;
#pragma unroll
  for (int it = 0; it * 256 < CH; ++it) {
    int chunk = it * 256 + tid;
    int row = chunk / (COLS / 4), cs = chunk % (COLS / 4);
    const float* g = src + (size_t)(row0 + row) * strideElts + col0 + cs * 4;
    float* l = lds + (size_t)(it * 256 + ((tid >> 6) << 6)) * 4;
    __builtin_amdgcn_global_load_lds(
        (const __attribute__((address_space(1))) unsigned int*)g,
        (__attribute__((address_space(3))) unsigned int*)l, 16, 0, AUXS);
  }
}

__device__ __forceinline__ short8 ldfrag(const unsigned short* lds, int row, int slot) {
  int s = slot ^ (row & 7);
  return *(const short8*)(lds + row * 64 + s * 8);
}

// Depth-2 counted-vmcnt GEMM mainloop (T3/T4): 3 LDS buffers, tile kt+2
// staged while computing kt; never drains vmcnt mid-loop. B tiles 0,1 must be
// prestaged (and drained) before entry; A tiles 0,1 + S extra loads issued here.
// PA==1 instr per A tile; PB per B tile; S = extra (lS) loads after A0,A1.
template <int NT, int PB, int S, typename SA, typename SB, typename SS, typename CC>
__device__ __forceinline__ void gloop(SA sa, SB sb, SS ss, CC cc) {
  sa(0, 0);
  sa(1, 1);
  ss();
#pragma unroll 1
  for (int kt = 0; kt < NT; ++kt) {
    if (kt == 0)
      asm volatile("s_waitcnt vmcnt(%0)" :: "i"(1 + S) : "memory");
    else if (kt == 1)
      asm volatile("s_waitcnt vmcnt(%0)" :: "i"(S + 1 + PB) : "memory");
    else if (kt < NT - 1)
      asm volatile("s_waitcnt vmcnt(%0)" :: "i"(1 + PB) : "memory");
    else
      asm volatile("s_waitcnt vmcnt(0)" ::: "memory");
    __builtin_amdgcn_s_barrier();
    __builtin_amdgcn_sched_barrier(0);
    if (kt + 2 < NT) { sa(kt + 2, (kt + 2) % 3); sb(kt + 2, (kt + 2) % 3); }
    cc(kt % 3);
  }
}

// 2-level fence-free global barrier, MONOTONIC counters (no reset races).
// p = 1,2,3,... strictly increasing per call, same sequence in every block.
__device__ __forceinline__ void gbar(unsigned* gcnt, unsigned* gen, unsigned* xcnt,
                                     unsigned p) {
  asm volatile("s_waitcnt vmcnt(0)" ::: "memory");  // all waves drain sc-stores
  __syncthreads();
  if (threadIdx.x == 0) {
    unsigned a = __hip_atomic_fetch_add(xcnt, 1u, __ATOMIC_RELAXED,
                                        __HIP_MEMORY_SCOPE_AGENT) + 1;
    if (a == p * 32) {  // last block of this XCD-group for phase p
      unsigned g2 = __hip_atomic_fetch_add(gcnt, 1u, __ATOMIC_RELAXED,
                                           __HIP_MEMORY_SCOPE_AGENT) + 1;
      if (g2 == p * 8) {
        __hip_atomic_store(gen, p, __ATOMIC_RELAXED, __HIP_MEMORY_SCOPE_AGENT);
      }
    }
    while (__hip_atomic_load(gen, __ATOMIC_RELAXED, __HIP_MEMORY_SCOPE_AGENT) < p)
      __builtin_amdgcn_s_sleep(2);
  }
  __syncthreads();
  __builtin_amdgcn_sched_barrier(0);
}

__global__ __launch_bounds__(256, 1) void k_fused(
    const float* __restrict__ xg, const float* __restrict__ xtime,
    const __hip_bfloat16* __restrict__ W1t, const float* __restrict__ b1,
    const __hip_bfloat16* __restrict__ W2t, const float* __restrict__ b2,
    const __hip_bfloat16* __restrict__ Wzrt, const float* __restrict__ bz,
    const float* __restrict__ br, const __hip_bfloat16* __restrict__ Wnt,
    const float* __restrict__ bn, float* __restrict__ hf, float* __restrict__ hstdf,
    float* __restrict__ hodef, float* __restrict__ zf,
    __hip_bfloat16* __restrict__ hbf, __hip_bfloat16* __restrict__ Ubf,
    __hip_bfloat16* __restrict__ hodeb, __hip_bfloat16* __restrict__ hstdb,
    __hip_bfloat16* __restrict__ A4, __hip_bfloat16* __restrict__ xstep,
    unsigned* __restrict__ bar) {
  __shared__ __align__(16) unsigned short lA[3][32 * 64];    // 12 KB
  __shared__ __align__(16) unsigned short lB[3][128 * 64];   // 48 KB
  __shared__ __align__(16) float lS0[32 * 128];              // 16 KB
  __shared__ __align__(16) float lS1[32 * 128];              // 16 KB
  int tid = threadIdx.x, lane = tid & 63, wv = tid >> 6;
  int lr = lane & 15, lg = lane >> 4;
  int b = blockIdx.x;
  int xd = b & 7;        // XCD group (round-robin heuristic; perf-only)
  int i = b >> 3;        // 0..31: batch strip index
  int m0 = i << 5;       // 32-row strip, pinned for all phases/steps
  int nA = xd << 6;      // P1/P2 n-slice base (64 cols)
  int wr = wv & 1, wc = wv >> 1;
  unsigned* gcnt = bar;
  unsigned* gen = bar + 32;
  unsigned* xcnt = bar + 64 + xd * 32;
  unsigned p = 0;

  // prestage P1 weight tiles 0,1 (L2-resident slice; drained by first gbar)
  stageT<64, 0>(W1t, H_SZ, nA, 0, lB[0], tid);
  stageT<64, 0>(W1t, H_SZ, nA, 64, lB[1], tid);

#pragma unroll 1
  for (int t = 0; t < T_SZ; ++t) {
    gbar(gcnt, gen, xcnt, ++p);  // h/hstd of step t-1 complete everywhere
    // ======== P1: U = tanh(h @ W1 + b1), strip x cols [nA,nA+64) ========
    {
      f32x4 acc[2] = {};
      auto sa = [&](int kt, int bi) { stageT<32, AUXS>(hbf, H_SZ, m0, kt << 6, lA[bi], tid); };
      auto sb = [&](int kt, int bi) { stageT<64, 0>(W1t, H_SZ, nA, kt << 6, lB[bi], tid); };
      auto ss = [&]() {};
      auto cc = [&](int bi) {
#pragma unroll
        for (int kk = 0; kk < 2; ++kk) {
          short8 a = ldfrag(lA[bi], (wr << 4) + lr, (kk << 2) + lg);
#pragma unroll
          for (int n = 0; n < 2; ++n) {
            short8 bb = ldfrag(lB[bi], (wc << 5) + (n << 4) + lr, (kk << 2) + lg);
            acc[n] = mfma16(a, bb, acc[n]);
          }
        }
      };
      gloop<8, 2, 0>(sa, sb, ss, cc);
#pragma unroll
      for (int n = 0; n < 2; ++n) {
        int col = nA + (wc << 5) + (n << 4) + lr;
        float bi = b1[col];
        int r0 = m0 + (wr << 4) + (lg << 2);
#pragma unroll
        for (int r = 0; r < 4; ++r)
          st_sys_bf16(&Ubf[(size_t)(r0 + r) * H_SZ + col], tanhf(acc[n][r] + bi));
      }
      stageT<64, 0>(W2t, H_SZ, nA, 0, lB[0], tid);   // prestage P2 weights
      stageT<64, 0>(W2t, H_SZ, nA, 64, lB[1], tid);
    }
    gbar(gcnt, gen, xcnt, ++p);
    // ======== P2: h_ode = h + dt*(U @ W2 + b2); x slice -> bf16 ========
    {
      f32x4 acc[2] = {};
      auto sa = [&](int kt, int bi) { stageT<32, AUXS>(Ubf, H_SZ, m0, kt << 6, lA[bi], tid); };
      auto sb = [&](int kt, int bi) { stageT<64, 0>(W2t, H_SZ, nA, kt << 6, lB[bi], tid); };
      auto ss = [&]() { stageF<32, 64>(hf, H_SZ, m0, nA, lS0, tid); };
      auto cc = [&](int bi) {
#pragma unroll
        for (int kk = 0; kk < 2; ++kk) {
          short8 a = ldfrag(lA[bi], (wr << 4) + lr, (kk << 2) + lg);
#pragma unroll
          for (int n = 0; n < 2; ++n) {
            short8 bb = ldfrag(lB[bi], (wc << 5) + (n << 4) + lr, (kk << 2) + lg);
            acc[n] = mfma16(a, bb, acc[n]);
          }
        }
      };
      gloop<8, 2, 2>(sa, sb, ss, cc);
      float dtv = (t == 0) ? 0.01f : (xtime[t] - xtime[t - 1]);
#pragma unroll
      for (int n = 0; n < 2; ++n) {
        int cl = (wc << 5) + (n << 4) + lr;
        int col = nA + cl;
        float bi = b2[col];
        int rl0 = (wr << 4) + (lg << 2);
#pragma unroll
        for (int r = 0; r < 4; ++r) {
          float v = lS0[(rl0 + r) * 64 + cl] + dtv * (acc[n][r] + bi);
          size_t ix = (size_t)(m0 + rl0 + r) * H_SZ + col;
          st_sys_f32(&hodef[ix], v);
          st_sys_bf16(&hodeb[ix], v);
        }
      }
      {  // x[:, t, xd-slice] -> bf16 (strip rows, 32 cols per XCD-group)
        int colx = (xd << 5) + (tid & 31);
#pragma unroll
        for (int it2 = 0; it2 < 4; ++it2) {
          int row = m0 + (tid >> 5) + (it2 << 3);
          float xv = xg[((size_t)row * T_SZ + t) * D_SZ + colx];
          st_sys_bf16(&xstep[(size_t)row * D_SZ + colx], xv);
        }
      }
      stageT<128, 0>(Wzrt, 1280, xd << 7, 0, lB[0], tid);   // prestage P3
      stageT<128, 0>(Wzrt, 1280, xd << 7, 64, lB[1], tid);
    }
    gbar(gcnt, gen, xcnt, ++p);
    // ======== P3: z|r = sigmoid(cat @ WzrT); strip x 128-col slice ========
    {
      f32x4 acc[4] = {};
      auto sa = [&](int kt, int bi) {
        int ke = kt << 6;
        if (ke < 512)       stageT<32, AUXS>(hodeb, H_SZ, m0, ke, lA[bi], tid);
        else if (ke < 1024) stageT<32, AUXS>(hstdb, H_SZ, m0, ke - 512, lA[bi], tid);
        else                stageT<32, AUXS>(xstep, D_SZ, m0, ke - 1024, lA[bi], tid);
      };
      auto sb = [&](int kt, int bi) { stageT<128, 0>(Wzrt, 1280, xd << 7, kt << 6, lB[bi], tid); };
      auto ss = [&]() {  // r-blocks consume; z-blocks stage (uniform count) & ignore
        stageF<32, 128>(hodef, H_SZ, m0, (xd & 3) << 7, lS0, tid);
        stageF<32, 128>(hstdf, H_SZ, m0, (xd & 3) << 7, lS1, tid);
      };
      auto cc = [&](int bi) {
#pragma unroll
        for (int kk = 0; kk < 2; ++kk) {
          short8 a = ldfrag(lA[bi], (wr << 4) + lr, (kk << 2) + lg);
#pragma unroll
          for (int n = 0; n < 4; ++n) {
            short8 bb = ldfrag(lB[bi], (wc << 6) + (n << 4) + lr, (kk << 2) + lg);
            acc[n] = mfma16(a, bb, acc[n]);
          }
        }
      };
      gloop<20, 4, 8>(sa, sb, ss, cc);
      int rl0 = (wr << 4) + (lg << 2);
      if (xd < 4) {  // z columns [xd*128, +128)
#pragma unroll
        for (int n = 0; n < 4; ++n) {
          int cl = (wc << 6) + (n << 4) + lr;
          int cg = (xd << 7) + cl;
          float bi = bz[cg];
#pragma unroll
          for (int r = 0; r < 4; ++r) {
            float g = 1.f / (1.f + expf(-(acc[n][r] + bi)));
            st_sys_f32(&zf[(size_t)(m0 + rl0 + r) * H_SZ + cg], g);
          }
        }
      } else {  // r columns -> A4 = [h_ode*r | hstd*r]
#pragma unroll
        for (int n = 0; n < 4; ++n) {
          int cl = (wc << 6) + (n << 4) + lr;
          int j = ((xd & 3) << 7) + cl;
          float bi = br[j];
#pragma unroll
          for (int r = 0; r < 4; ++r) {
            int row = m0 + rl0 + r;
            float g = 1.f / (1.f + expf(-(acc[n][r] + bi)));
            st_sys_bf16(&A4[(size_t)row * 1024 + j], lS0[(rl0 + r) * 128 + cl] * g);
            st_sys_bf16(&A4[(size_t)row * 1024 + 512 + j], lS1[(rl0 + r) * 128 + cl] * g);
          }
        }
      }
      stageT<128, 0>(Wnt, 1280, xd << 7, 0, lB[0], tid);   // prestage P4
      stageT<128, 0>(Wnt, 1280, xd << 7, 64, lB[1], tid);
    }
    gbar(gcnt, gen, xcnt, ++p);
    // ======== P4: n = cat_r @ Wn + bn; GRU update; strip x 128-col slice ====
    {
      f32x4 acc[4] = {};
      auto sa = [&](int kt, int bi) {
        int ke = kt << 6;
        if (ke < 1024) stageT<32, AUXS>(A4, 1024, m0, ke, lA[bi], tid);
        else           stageT<32, AUXS>(xstep, D_SZ, m0, ke - 1024, lA[bi], tid);
      };
      auto sb = [&](int kt, int bi) { stageT<128, 0>(Wnt, 1280, xd << 7, kt << 6, lB[bi], tid); };
      const float* s1src = (xd < 4) ? hodef : hstdf;
      auto ss = [&]() {
        stageF<32, 128>(zf, H_SZ, m0, (xd & 3) << 7, lS0, tid);
        stageF<32, 128>(s1src, H_SZ, m0, (xd & 3) << 7, lS1, tid);
      };
      auto cc = [&](int bi) {
#pragma unroll
        for (int kk = 0; kk < 2; ++kk) {
          short8 a = ldfrag(lA[bi], (wr << 4) + lr, (kk << 2) + lg);
#pragma unroll
          for (int n = 0; n < 4; ++n) {
            short8 bb = ldfrag(lB[bi], (wc << 6) + (n << 4) + lr, (kk << 2) + lg);
            acc[n] = mfma16(a, bb, acc[n]);
          }
        }
      };
      gloop<20, 4, 8>(sa, sb, ss, cc);
      int rl0 = (wr << 4) + (lg << 2);
      if (xd < 4) {  // mean columns -> h update
#pragma unroll
        for (int n = 0; n < 4; ++n) {
          int cl = (wc << 6) + (n << 4) + lr;
          int c = (xd << 7) + cl;
          float bi = bn[c];
#pragma unroll
          for (int r = 0; r < 4; ++r) {
            size_t ix = (size_t)(m0 + rl0 + r) * H_SZ + c;
            float nm = acc[n][r] + bi;
            float z = lS0[(rl0 + r) * 128 + cl], ho = lS1[(rl0 + r) * 128 + cl];
            float hn = (1.f - z) * nm + z * ho;
            st_sys_f32(&hf[ix], hn);
            st_sys_bf16(&hbf[ix], hn);
          }
        }
      } else {  // std columns -> hstd update
#pragma unroll
        for (int n = 0; n < 4; ++n) {
          int cl = (wc << 6) + (n << 4) + lr;
          int j = ((xd & 3) << 7) + cl;
          float bi = bn[512 + j];
#pragma unroll
          for (int r = 0; r < 4; ++r) {
            size_t ix = (size_t)(m0 + rl0 + r) * H_SZ + j;
            float ns = fabsf(acc[n][r] + bi);
            float z = lS0[(rl0 + r) * 128 + cl], hs = lS1[(rl0 + r) * 128 + cl];
            float sn = fabsf((1.f - z) * ns + z * hs);
            st_sys_f32(&hstdf[ix], sn);
            st_sys_bf16(&hstdb[ix], sn);
          }
        }
      }
      stageT<64, 0>(W1t, H_SZ, nA, 0, lB[0], tid);   // prestage next-step P1
      stageT<64, 0>(W1t, H_SZ, nA, 64, lB[1], tid);
    }
  }
}

// =============== prep: W[k][n] f32  ->  Wt[n][k] bf16 =====================
__global__ void k_wt(const float* __restrict__ W, __hip_bfloat16* __restrict__ Wt,
                     int K, int N, int ld) {
  size_t i = (size_t)blockIdx.x * 256 + threadIdx.x;
  if (i >= (size_t)K * N) return;
  int n = (int)(i / K), k = (int)(i % K);
  Wt[(size_t)n * ld + k] = __float2bfloat16(W[(size_t)k * N + n]);
}

extern "C" void kernel_launch(void* const* d_in, const int* in_sizes, int n_in,
                              void* d_out, int out_size, void* d_ws, size_t ws_size,
                              hipStream_t stream) {
  const float* x     = (const float*)d_in[0];
  const float* xtime = (const float*)d_in[1];
  const float* W1    = (const float*)d_in[2];
  const float* b1    = (const float*)d_in[3];
  const float* W2    = (const float*)d_in[4];
  const float* b2    = (const float*)d_in[5];
  const float* Wz    = (const float*)d_in[6];
  const float* bz    = (const float*)d_in[7];
  const float* Wr    = (const float*)d_in[8];
  const float* br    = (const float*)d_in[9];
  const float* Wn    = (const float*)d_in[10];
  const float* bn    = (const float*)d_in[11];

  char* p = (char*)d_ws;
  __hip_bfloat16* W1t   = (__hip_bfloat16*)(p + 0);
  __hip_bfloat16* W2t   = (__hip_bfloat16*)(p + 524288);
  __hip_bfloat16* Wzrt  = (__hip_bfloat16*)(p + 1048576);
  __hip_bfloat16* Wnt   = (__hip_bfloat16*)(p + 3670016);
  float*          hf    = (float*)(p + 6291456);
  float*          hstdf = (float*)(p + 8388608);
  float*          hodef = (float*)(p + 10485760);
  float*          zf    = (float*)(p + 12582912);
  __hip_bfloat16* hbf   = (__hip_bfloat16*)(p + 14680064);
  __hip_bfloat16* Ubf   = (__hip_bfloat16*)(p + 15728640);
  __hip_bfloat16* hodeb = (__hip_bfloat16*)(p + 16777216);
  __hip_bfloat16* hstdb = (__hip_bfloat16*)(p + 17825792);
  __hip_bfloat16* A4    = (__hip_bfloat16*)(p + 18874368);
  __hip_bfloat16* xstep = (__hip_bfloat16*)(p + 20971520);
  unsigned*       bar   = (unsigned*)(p + 21495808);

  hipMemsetAsync(hf, 0, 2097152, stream);
  hipMemsetAsync(hstdf, 0, 2097152, stream);
  hipMemsetAsync(hbf, 0, 1048576, stream);
  hipMemsetAsync(hstdb, 0, 1048576, stream);
  hipMemsetAsync(bar, 0, 4096, stream);

  k_wt<<<(512 * 512 + 255) / 256, 256, 0, stream>>>(W1, W1t, 512, 512, 512);
  k_wt<<<(512 * 512 + 255) / 256, 256, 0, stream>>>(W2, W2t, 512, 512, 512);
  k_wt<<<(1280 * 512 + 255) / 256, 256, 0, stream>>>(Wz, Wzrt, 1280, 512, 1280);
  k_wt<<<(1280 * 512 + 255) / 256, 256, 0, stream>>>(Wr, Wzrt + (size_t)512 * 1280, 1280, 512, 1280);
  k_wt<<<(1280 * 1024 + 255) / 256, 256, 0, stream>>>(Wn, Wnt, 1280, 1024, 1280);

  // persistent kernel: weights n-sliced per XCD-group (L2-resident),
  // batch-strip blocks, 2-level monotonic global barrier per phase
  k_fused<<<NBLK, 256, 0, stream>>>(x, xtime, W1t, b1, W2t, b2, Wzrt, bz, br,
                                    Wnt, bn, hf, hstdf, hodef, zf, hbf, Ubf,
                                    hodeb, hstdb, A4, xstep, bar);

  hipMemcpyAsync(d_out, hf, 2097152, hipMemcpyDeviceToDevice, stream);
  hipMemcpyAsync((char*)d_out + 2097152, hstdf, 2097152, hipMemcpyDeviceToDevice, stream);
}

// Round 7
// 7451.313 us; speedup vs baseline: 3.2042x; 1.0896x over previous
//
#include <hip/hip_runtime.h>
#include <hip/hip_bf16.h>

#define B_SZ 1024
#define T_SZ 128
#define D_SZ 256
#define H_SZ 512
#define NBLK 256
#define AUXS 0x11   // CPol SC0|SC1: system-coherent, bypass L1/L2 (state path)

typedef __attribute__((ext_vector_type(8))) short short8;
typedef __attribute__((ext_vector_type(4))) float f32x4;

__device__ inline f32x4 mfma16(short8 a, short8 b, f32x4 c) {
  return __builtin_amdgcn_mfma_f32_16x16x32_bf16(a, b, c, 0, 0, 0);
}

__device__ inline void st_sys_f32(float* p, float v) {
  asm volatile("global_store_dword %0, %1, off sc0 sc1" :: "v"(p), "v"(v) : "memory");
}
__device__ inline void st_sys_bf16(__hip_bfloat16* p, float v) {
  union { __hip_bfloat16 b; unsigned short u; } cv;
  cv.b = __float2bfloat16(v);
  unsigned int vv = cv.u;
  asm volatile("global_store_short %0, %1, off sc0 sc1" :: "v"(p), "v"(vv) : "memory");
}

// Stage ROWSx64 bf16 tile -> LDS [ROWS][64], slot-swizzled (slot s of row r
// holds k-slot s^(r&7)); linear LDS dest + inverse-swizzled global source.
template <int ROWS, int AUX>
__device__ __forceinline__ void stageT(const __hip_bfloat16* __restrict__ src,
                                       int strideElts, int row0, int k0,
                                       unsigned short* lds, int tid) {
  constexpr int CH = ROWS * 8;
#pragma unroll
  for (int it = 0; it * 256 < CH; ++it) {
    int chunk = it * 256 + tid;
    int row = chunk >> 3, slot = chunk & 7;
    int ksrc = (slot ^ (row & 7)) << 3;
    const __hip_bfloat16* g = src + (size_t)(row0 + row) * strideElts + (k0 + ksrc);
    unsigned short* l = lds + (size_t)(it * 256 + ((tid >> 6) << 6)) * 8;
    __builtin_amdgcn_global_load_lds(
        (const __attribute__((address_space(1))) unsigned int*)g,
        (__attribute__((address_space(3))) unsigned int*)l, 16, 0, AUX);
  }
}

// Stage ROWSxCOLS f32 tile -> LDS linear row-major, system-coherent.
template <int ROWS, int COLS>
__device__ __forceinline__ void stageF(const float* __restrict__ src, int strideElts,
                                       int row0, int col0, float* lds, int tid) {
  constexpr int CH = ROWS * COLS / 4;
#pragma unroll
  for (int it = 0; it * 256 < CH; ++it) {
    int chunk = it * 256 + tid;
    int row = chunk / (COLS / 4), cs = chunk % (COLS / 4);
    const float* g = src + (size_t)(row0 + row) * strideElts + col0 + cs * 4;
    float* l = lds + (size_t)(it * 256 + ((tid >> 6) << 6)) * 4;
    __builtin_amdgcn_global_load_lds(
        (const __attribute__((address_space(1))) unsigned int*)g,
        (__attribute__((address_space(3))) unsigned int*)l, 16, 0, AUXS);
  }
}

__device__ __forceinline__ short8 ldfrag(const unsigned short* lds, int row, int slot) {
  int s = slot ^ (row & 7);
  return *(const short8*)(lds + row * 64 + s * 8);
}

// Depth-2 counted-vmcnt GEMM mainloop (T3/T4): 3 LDS buffers, tile kt+2
// staged while computing kt; never drains vmcnt mid-loop. B tiles 0,1 must be
// prestaged (and drained) before entry; A tiles 0,1 + S extra loads issued here.
template <int NT, int PB, int S, typename SA, typename SB, typename SS, typename CC>
__device__ __forceinline__ void gloop(SA sa, SB sb, SS ss, CC cc) {
  sa(0, 0);
  sa(1, 1);
  ss();
#pragma unroll 1
  for (int kt = 0; kt < NT; ++kt) {
    if (kt == 0)
      asm volatile("s_waitcnt vmcnt(%0)" :: "i"(1 + S) : "memory");
    else if (kt == 1)
      asm volatile("s_waitcnt vmcnt(%0)" :: "i"(S + 1 + PB) : "memory");
    else if (kt < NT - 1)
      asm volatile("s_waitcnt vmcnt(%0)" :: "i"(1 + PB) : "memory");
    else
      asm volatile("s_waitcnt vmcnt(0)" ::: "memory");
    __builtin_amdgcn_s_barrier();
    __builtin_amdgcn_sched_barrier(0);
    if (kt + 2 < NT) { sa(kt + 2, (kt + 2) % 3); sb(kt + 2, (kt + 2) % 3); }
    cc(kt % 3);
  }
}

// Strip-local 8-block barrier: monotonic counter, relaxed atomics, no fences.
// All phase dependencies are contained in the 8 blocks sharing one 32-row
// strip (weights are read-only), so no global sync is needed. p = 1,2,3,...
__device__ __forceinline__ void sbar(unsigned* scnt, unsigned p) {
  asm volatile("s_waitcnt vmcnt(0)" ::: "memory");  // all waves drain sc-stores
  __syncthreads();
  if (threadIdx.x == 0) {
    __hip_atomic_fetch_add(scnt, 1u, __ATOMIC_RELAXED, __HIP_MEMORY_SCOPE_AGENT);
    while (__hip_atomic_load(scnt, __ATOMIC_RELAXED, __HIP_MEMORY_SCOPE_AGENT) < p * 8u)
      __builtin_amdgcn_s_sleep(1);
  }
  __syncthreads();
  __builtin_amdgcn_sched_barrier(0);
}

__global__ __launch_bounds__(256, 1) void k_fused(
    const float* __restrict__ xg, const float* __restrict__ xtime,
    const __hip_bfloat16* __restrict__ W1t, const float* __restrict__ b1,
    const __hip_bfloat16* __restrict__ W2t, const float* __restrict__ b2,
    const __hip_bfloat16* __restrict__ Wzrt, const float* __restrict__ bz,
    const float* __restrict__ br, const __hip_bfloat16* __restrict__ Wnt,
    const float* __restrict__ bn, float* __restrict__ hf, float* __restrict__ hstdf,
    float* __restrict__ hodef, float* __restrict__ zf,
    __hip_bfloat16* __restrict__ hbf, __hip_bfloat16* __restrict__ Ubf,
    __hip_bfloat16* __restrict__ hodeb, __hip_bfloat16* __restrict__ hstdb,
    __hip_bfloat16* __restrict__ A4, __hip_bfloat16* __restrict__ xstep,
    unsigned* __restrict__ bar) {
  __shared__ __align__(16) unsigned short lA[3][32 * 64];    // 12 KB
  __shared__ __align__(16) unsigned short lB[3][128 * 64];   // 48 KB
  __shared__ __align__(16) float lS0[32 * 128];              // 16 KB
  __shared__ __align__(16) float lS1[32 * 128];              // 16 KB
  int tid = threadIdx.x, lane = tid & 63, wv = tid >> 6;
  int lr = lane & 15, lg = lane >> 4;
  int b = blockIdx.x;
  int xd = b & 7;        // XCD group (round-robin heuristic; perf-only)
  int i = b >> 3;        // 0..31: batch strip index
  int m0 = i << 5;       // 32-row strip, pinned for all phases/steps
  int nA = xd << 6;      // P1/P2 n-slice base (64 cols)
  int wr = wv & 1, wc = wv >> 1;
  unsigned* scnt = bar + i * 32;   // per-strip 128B counter line
  unsigned p = 0;

  // prestage P1 weight tiles 0,1 (L2-resident slice; drained by first sbar)
  stageT<64, 0>(W1t, H_SZ, nA, 0, lB[0], tid);
  stageT<64, 0>(W1t, H_SZ, nA, 64, lB[1], tid);

#pragma unroll 1
  for (int t = 0; t < T_SZ; ++t) {
    sbar(scnt, ++p);  // strip's h/hstd of step t-1 complete
    // ======== P1: U = tanh(h @ W1 + b1), strip x cols [nA,nA+64) ========
    {
      f32x4 acc[2] = {};
      auto sa = [&](int kt, int bi) { stageT<32, AUXS>(hbf, H_SZ, m0, kt << 6, lA[bi], tid); };
      auto sb = [&](int kt, int bi) { stageT<64, 0>(W1t, H_SZ, nA, kt << 6, lB[bi], tid); };
      auto ss = [&]() {};
      auto cc = [&](int bi) {
#pragma unroll
        for (int kk = 0; kk < 2; ++kk) {
          short8 a = ldfrag(lA[bi], (wr << 4) + lr, (kk << 2) + lg);
#pragma unroll
          for (int n = 0; n < 2; ++n) {
            short8 bb = ldfrag(lB[bi], (wc << 5) + (n << 4) + lr, (kk << 2) + lg);
            acc[n] = mfma16(a, bb, acc[n]);
          }
        }
      };
      gloop<8, 2, 0>(sa, sb, ss, cc);
#pragma unroll
      for (int n = 0; n < 2; ++n) {
        int col = nA + (wc << 5) + (n << 4) + lr;
        float bi = b1[col];
        int r0 = m0 + (wr << 4) + (lg << 2);
#pragma unroll
        for (int r = 0; r < 4; ++r)
          st_sys_bf16(&Ubf[(size_t)(r0 + r) * H_SZ + col], tanhf(acc[n][r] + bi));
      }
      stageT<64, 0>(W2t, H_SZ, nA, 0, lB[0], tid);   // prestage P2 weights
      stageT<64, 0>(W2t, H_SZ, nA, 64, lB[1], tid);
    }
    sbar(scnt, ++p);
    // ======== P2: h_ode = h + dt*(U @ W2 + b2); x slice -> bf16 ========
    {
      f32x4 acc[2] = {};
      auto sa = [&](int kt, int bi) { stageT<32, AUXS>(Ubf, H_SZ, m0, kt << 6, lA[bi], tid); };
      auto sb = [&](int kt, int bi) { stageT<64, 0>(W2t, H_SZ, nA, kt << 6, lB[bi], tid); };
      auto ss = [&]() { stageF<32, 64>(hf, H_SZ, m0, nA, lS0, tid); };
      auto cc = [&](int bi) {
#pragma unroll
        for (int kk = 0; kk < 2; ++kk) {
          short8 a = ldfrag(lA[bi], (wr << 4) + lr, (kk << 2) + lg);
#pragma unroll
          for (int n = 0; n < 2; ++n) {
            short8 bb = ldfrag(lB[bi], (wc << 5) + (n << 4) + lr, (kk << 2) + lg);
            acc[n] = mfma16(a, bb, acc[n]);
          }
        }
      };
      gloop<8, 2, 2>(sa, sb, ss, cc);
      float dtv = (t == 0) ? 0.01f : (xtime[t] - xtime[t - 1]);
#pragma unroll
      for (int n = 0; n < 2; ++n) {
        int cl = (wc << 5) + (n << 4) + lr;
        int col = nA + cl;
        float bi = b2[col];
        int rl0 = (wr << 4) + (lg << 2);
#pragma unroll
        for (int r = 0; r < 4; ++r) {
          float v = lS0[(rl0 + r) * 64 + cl] + dtv * (acc[n][r] + bi);
          size_t ix = (size_t)(m0 + rl0 + r) * H_SZ + col;
          st_sys_f32(&hodef[ix], v);
          st_sys_bf16(&hodeb[ix], v);
        }
      }
      {  // x[:, t, xd-slice] -> bf16 (strip rows, 32 cols per XCD-group)
        int colx = (xd << 5) + (tid & 31);
#pragma unroll
        for (int it2 = 0; it2 < 4; ++it2) {
          int row = m0 + (tid >> 5) + (it2 << 3);
          float xv = xg[((size_t)row * T_SZ + t) * D_SZ + colx];
          st_sys_bf16(&xstep[(size_t)row * D_SZ + colx], xv);
        }
      }
      stageT<128, 0>(Wzrt, 1280, xd << 7, 0, lB[0], tid);   // prestage P3
      stageT<128, 0>(Wzrt, 1280, xd << 7, 64, lB[1], tid);
    }
    sbar(scnt, ++p);
    // ======== P3: z|r = sigmoid(cat @ WzrT); strip x 128-col slice ========
    {
      f32x4 acc[4] = {};
      auto sa = [&](int kt, int bi) {
        int ke = kt << 6;
        if (ke < 512)       stageT<32, AUXS>(hodeb, H_SZ, m0, ke, lA[bi], tid);
        else if (ke < 1024) stageT<32, AUXS>(hstdb, H_SZ, m0, ke - 512, lA[bi], tid);
        else                stageT<32, AUXS>(xstep, D_SZ, m0, ke - 1024, lA[bi], tid);
      };
      auto sb = [&](int kt, int bi) { stageT<128, 0>(Wzrt, 1280, xd << 7, kt << 6, lB[bi], tid); };
      auto ss = [&]() {  // r-blocks consume; z-blocks stage (uniform count) & ignore
        stageF<32, 128>(hodef, H_SZ, m0, (xd & 3) << 7, lS0, tid);
        stageF<32, 128>(hstdf, H_SZ, m0, (xd & 3) << 7, lS1, tid);
      };
      auto cc = [&](int bi) {
#pragma unroll
        for (int kk = 0; kk < 2; ++kk) {
          short8 a = ldfrag(lA[bi], (wr << 4) + lr, (kk << 2) + lg);
#pragma unroll
          for (int n = 0; n < 4; ++n) {
            short8 bb = ldfrag(lB[bi], (wc << 6) + (n << 4) + lr, (kk << 2) + lg);
            acc[n] = mfma16(a, bb, acc[n]);
          }
        }
      };
      gloop<20, 4, 8>(sa, sb, ss, cc);
      int rl0 = (wr << 4) + (lg << 2);
      if (xd < 4) {  // z columns [xd*128, +128)
#pragma unroll
        for (int n = 0; n < 4; ++n) {
          int cl = (wc << 6) + (n << 4) + lr;
          int cg = (xd << 7) + cl;
          float bi = bz[cg];
#pragma unroll
          for (int r = 0; r < 4; ++r) {
            float g = 1.f / (1.f + expf(-(acc[n][r] + bi)));
            st_sys_f32(&zf[(size_t)(m0 + rl0 + r) * H_SZ + cg], g);
          }
        }
      } else {  // r columns -> A4 = [h_ode*r | hstd*r]
#pragma unroll
        for (int n = 0; n < 4; ++n) {
          int cl = (wc << 6) + (n << 4) + lr;
          int j = ((xd & 3) << 7) + cl;
          float bi = br[j];
#pragma unroll
          for (int r = 0; r < 4; ++r) {
            int row = m0 + rl0 + r;
            float g = 1.f / (1.f + expf(-(acc[n][r] + bi)));
            st_sys_bf16(&A4[(size_t)row * 1024 + j], lS0[(rl0 + r) * 128 + cl] * g);
            st_sys_bf16(&A4[(size_t)row * 1024 + 512 + j], lS1[(rl0 + r) * 128 + cl] * g);
          }
        }
      }
      stageT<128, 0>(Wnt, 1280, xd << 7, 0, lB[0], tid);   // prestage P4
      stageT<128, 0>(Wnt, 1280, xd << 7, 64, lB[1], tid);
    }
    sbar(scnt, ++p);
    // ======== P4: n = cat_r @ Wn + bn; GRU update; strip x 128-col slice ====
    {
      f32x4 acc[4] = {};
      auto sa = [&](int kt, int bi) {
        int ke = kt << 6;
        if (ke < 1024) stageT<32, AUXS>(A4, 1024, m0, ke, lA[bi], tid);
        else           stageT<32, AUXS>(xstep, D_SZ, m0, ke - 1024, lA[bi], tid);
      };
      auto sb = [&](int kt, int bi) { stageT<128, 0>(Wnt, 1280, xd << 7, kt << 6, lB[bi], tid); };
      const float* s1src = (xd < 4) ? hodef : hstdf;
      auto ss = [&]() {
        stageF<32, 128>(zf, H_SZ, m0, (xd & 3) << 7, lS0, tid);
        stageF<32, 128>(s1src, H_SZ, m0, (xd & 3) << 7, lS1, tid);
      };
      auto cc = [&](int bi) {
#pragma unroll
        for (int kk = 0; kk < 2; ++kk) {
          short8 a = ldfrag(lA[bi], (wr << 4) + lr, (kk << 2) + lg);
#pragma unroll
          for (int n = 0; n < 4; ++n) {
            short8 bb = ldfrag(lB[bi], (wc << 6) + (n << 4) + lr, (kk << 2) + lg);
            acc[n] = mfma16(a, bb, acc[n]);
          }
        }
      };
      gloop<20, 4, 8>(sa, sb, ss, cc);
      int rl0 = (wr << 4) + (lg << 2);
      if (xd < 4) {  // mean columns -> h update
#pragma unroll
        for (int n = 0; n < 4; ++n) {
          int cl = (wc << 6) + (n << 4) + lr;
          int c = (xd << 7) + cl;
          float bi = bn[c];
#pragma unroll
          for (int r = 0; r < 4; ++r) {
            size_t ix = (size_t)(m0 + rl0 + r) * H_SZ + c;
            float nm = acc[n][r] + bi;
            float z = lS0[(rl0 + r) * 128 + cl], ho = lS1[(rl0 + r) * 128 + cl];
            float hn = (1.f - z) * nm + z * ho;
            st_sys_f32(&hf[ix], hn);
            st_sys_bf16(&hbf[ix], hn);
          }
        }
      } else {  // std columns -> hstd update
#pragma unroll
        for (int n = 0; n < 4; ++n) {
          int cl = (wc << 6) + (n << 4) + lr;
          int j = ((xd & 3) << 7) + cl;
          float bi = bn[512 + j];
#pragma unroll
          for (int r = 0; r < 4; ++r) {
            size_t ix = (size_t)(m0 + rl0 + r) * H_SZ + j;
            float ns = fabsf(acc[n][r] + bi);
            float z = lS0[(rl0 + r) * 128 + cl], hs = lS1[(rl0 + r) * 128 + cl];
            float sn = fabsf((1.f - z) * ns + z * hs);
            st_sys_f32(&hstdf[ix], sn);
            st_sys_bf16(&hstdb[ix], sn);
          }
        }
      }
      stageT<64, 0>(W1t, H_SZ, nA, 0, lB[0], tid);   // prestage next-step P1
      stageT<64, 0>(W1t, H_SZ, nA, 64, lB[1], tid);
    }
  }
}

// =============== prep: W[k][n] f32  ->  Wt[n][k] bf16 =====================
__global__ void k_wt(const float* __restrict__ W, __hip_bfloat16* __restrict__ Wt,
                     int K, int N, int ld) {
  size_t i = (size_t)blockIdx.x * 256 + threadIdx.x;
  if (i >= (size_t)K * N) return;
  int n = (int)(i / K), k = (int)(i % K);
  Wt[(size_t)n * ld + k] = __float2bfloat16(W[(size_t)k * N + n]);
}

extern "C" void kernel_launch(void* const* d_in, const int* in_sizes, int n_in,
                              void* d_out, int out_size, void* d_ws, size_t ws_size,
                              hipStream_t stream) {
  const float* x     = (const float*)d_in[0];
  const float* xtime = (const float*)d_in[1];
  const float* W1    = (const float*)d_in[2];
  const float* b1    = (const float*)d_in[3];
  const float* W2    = (const float*)d_in[4];
  const float* b2    = (const float*)d_in[5];
  const float* Wz    = (const float*)d_in[6];
  const float* bz    = (const float*)d_in[7];
  const float* Wr    = (const float*)d_in[8];
  const float* br    = (const float*)d_in[9];
  const float* Wn    = (const float*)d_in[10];
  const float* bn    = (const float*)d_in[11];

  char* p = (char*)d_ws;
  __hip_bfloat16* W1t   = (__hip_bfloat16*)(p + 0);
  __hip_bfloat16* W2t   = (__hip_bfloat16*)(p + 524288);
  __hip_bfloat16* Wzrt  = (__hip_bfloat16*)(p + 1048576);
  __hip_bfloat16* Wnt   = (__hip_bfloat16*)(p + 3670016);
  float*          hf    = (float*)(p + 6291456);
  float*          hstdf = (float*)(p + 8388608);
  float*          hodef = (float*)(p + 10485760);
  float*          zf    = (float*)(p + 12582912);
  __hip_bfloat16* hbf   = (__hip_bfloat16*)(p + 14680064);
  __hip_bfloat16* Ubf   = (__hip_bfloat16*)(p + 15728640);
  __hip_bfloat16* hodeb = (__hip_bfloat16*)(p + 16777216);
  __hip_bfloat16* hstdb = (__hip_bfloat16*)(p + 17825792);
  __hip_bfloat16* A4    = (__hip_bfloat16*)(p + 18874368);
  __hip_bfloat16* xstep = (__hip_bfloat16*)(p + 20971520);
  unsigned*       bar   = (unsigned*)(p + 21495808);

  hipMemsetAsync(hf, 0, 2097152, stream);
  hipMemsetAsync(hstdf, 0, 2097152, stream);
  hipMemsetAsync(hbf, 0, 1048576, stream);
  hipMemsetAsync(hstdb, 0, 1048576, stream);
  hipMemsetAsync(bar, 0, 4096, stream);

  k_wt<<<(512 * 512 + 255) / 256, 256, 0, stream>>>(W1, W1t, 512, 512, 512);
  k_wt<<<(512 * 512 + 255) / 256, 256, 0, stream>>>(W2, W2t, 512, 512, 512);
  k_wt<<<(1280 * 512 + 255) / 256, 256, 0, stream>>>(Wz, Wzrt, 1280, 512, 1280);
  k_wt<<<(1280 * 512 + 255) / 256, 256, 0, stream>>>(Wr, Wzrt + (size_t)512 * 1280, 1280, 512, 1280);
  k_wt<<<(1280 * 1024 + 255) / 256, 256, 0, stream>>>(Wn, Wnt, 1280, 1024, 1280);

  // persistent kernel: weights n-sliced per XCD-group (L2-resident),
  // strip-local 8-block barriers only (no global sync)
  k_fused<<<NBLK, 256, 0, stream>>>(x, xtime, W1t, b1, W2t, b2, Wzrt, bz, br,
                                    Wnt, bn, hf, hstdf, hodef, zf, hbf, Ubf,
                                    hodeb, hstdb, A4, xstep, bar);

  hipMemcpyAsync(d_out, hf, 2097152, hipMemcpyDeviceToDevice, stream);
  hipMemcpyAsync((char*)d_out + 2097152, hstdf, 2097152, hipMemcpyDeviceToDevice, stream);
}

// Round 8
// 7108.739 us; speedup vs baseline: 3.3586x; 1.0482x over previous
//
#include <hip/hip_runtime.h>
#include <hip/hip_bf16.h>

#define B_SZ 1024
#define T_SZ 128
#define D_SZ 256
#define H_SZ 512
#define NBLK 512
#define AUXS 0x11   // CPol SC0|SC1: system-coherent, bypass L1/L2 (state path)

typedef __attribute__((ext_vector_type(8))) short short8;
typedef __attribute__((ext_vector_type(4))) float f32x4;

__device__ inline f32x4 mfma16(short8 a, short8 b, f32x4 c) {
  return __builtin_amdgcn_mfma_f32_16x16x32_bf16(a, b, c, 0, 0, 0);
}

__device__ inline void st_sys_f32(float* p, float v) {
  asm volatile("global_store_dword %0, %1, off sc0 sc1" :: "v"(p), "v"(v) : "memory");
}
__device__ inline void st_sys_bf16(__hip_bfloat16* p, float v) {
  union { __hip_bfloat16 b; unsigned short u; } cv;
  cv.b = __float2bfloat16(v);
  unsigned int vv = cv.u;
  asm volatile("global_store_short %0, %1, off sc0 sc1" :: "v"(p), "v"(vv) : "memory");
}

// Stage ROWSx64 bf16 tile -> LDS [ROWS][64], slot-swizzled (slot s of row r
// holds k-slot s^(r&7)); linear LDS dest + inverse-swizzled global source.
// Wave-uniform guard handles ROWS*8 < 256 (idle waves issue nothing).
template <int ROWS, int AUX>
__device__ __forceinline__ void stageT(const __hip_bfloat16* __restrict__ src,
                                       int strideElts, int row0, int k0,
                                       unsigned short* lds, int tid) {
  constexpr int CH = ROWS * 8;
#pragma unroll
  for (int it = 0; it * 256 < CH; ++it) {
    int wbase = it * 256 + ((tid >> 6) << 6);
    if (wbase < CH) {
      int chunk = it * 256 + tid;
      int row = chunk >> 3, slot = chunk & 7;
      int ksrc = (slot ^ (row & 7)) << 3;
      const __hip_bfloat16* g = src + (size_t)(row0 + row) * strideElts + (k0 + ksrc);
      unsigned short* l = lds + (size_t)wbase * 8;
      __builtin_amdgcn_global_load_lds(
          (const __attribute__((address_space(1))) unsigned int*)g,
          (__attribute__((address_space(3))) unsigned int*)l, 16, 0, AUX);
    }
  }
}

// Stage ROWSxCOLS f32 tile -> LDS linear row-major, system-coherent.
template <int ROWS, int COLS>
__device__ __forceinline__ void stageF(const float* __restrict__ src, int strideElts,
                                       int row0, int col0, float* lds, int tid) {
  constexpr int CH = ROWS * COLS / 4;
#pragma unroll
  for (int it = 0; it * 256 < CH; ++it) {
    int chunk = it * 256 + tid;
    int row = chunk / (COLS / 4), cs = chunk % (COLS / 4);
    const float* g = src + (size_t)(row0 + row) * strideElts + col0 + cs * 4;
    float* l = lds + (size_t)(it * 256 + ((tid >> 6) << 6)) * 4;
    __builtin_amdgcn_global_load_lds(
        (const __attribute__((address_space(1))) unsigned int*)g,
        (__attribute__((address_space(3))) unsigned int*)l, 16, 0, AUXS);
  }
}

__device__ __forceinline__ short8 ldfrag(const unsigned short* lds, int row, int slot) {
  int s = slot ^ (row & 7);
  return *(const short8*)(lds + row * 64 + s * 8);
}

// Depth-2 counted-vmcnt GEMM mainloop (T3/T4): 3 LDS buffers, tile kt+2
// staged while computing kt; never drains vmcnt mid-loop. B tiles 0,1 must be
// prestaged before entry (drained by the preceding sbar's vmcnt(0)).
template <int NT, int PB, int S, typename SA, typename SB, typename SS, typename CC>
__device__ __forceinline__ void gloop(SA sa, SB sb, SS ss, CC cc) {
  sa(0, 0);
  sa(1, 1);
  ss();
#pragma unroll 1
  for (int kt = 0; kt < NT; ++kt) {
    if (kt == 0)
      asm volatile("s_waitcnt vmcnt(%0)" :: "i"(1 + S) : "memory");
    else if (kt == 1)
      asm volatile("s_waitcnt vmcnt(%0)" :: "i"(S + 1 + PB) : "memory");
    else if (kt < NT - 1)
      asm volatile("s_waitcnt vmcnt(%0)" :: "i"(1 + PB) : "memory");
    else
      asm volatile("s_waitcnt vmcnt(0)" ::: "memory");
    __builtin_amdgcn_s_barrier();
    __builtin_amdgcn_sched_barrier(0);
    if (kt + 2 < NT) { sa(kt + 2, (kt + 2) % 3); sb(kt + 2, (kt + 2) % 3); }
    cc(kt % 3);
  }
}

// Strip-local 8-block barrier: monotonic counter, relaxed atomics, no fences.
// All phase deps are within the 8 blocks sharing one 16-row strip. p=1,2,...
__device__ __forceinline__ void sbar(unsigned* scnt, unsigned p) {
  asm volatile("s_waitcnt vmcnt(0)" ::: "memory");  // all waves drain sc-stores
  __syncthreads();
  if (threadIdx.x == 0) {
    __hip_atomic_fetch_add(scnt, 1u, __ATOMIC_RELAXED, __HIP_MEMORY_SCOPE_AGENT);
    while (__hip_atomic_load(scnt, __ATOMIC_RELAXED, __HIP_MEMORY_SCOPE_AGENT) < p * 8u)
      __builtin_amdgcn_s_sleep(1);
  }
  __syncthreads();
  __builtin_amdgcn_sched_barrier(0);
}

__global__ __launch_bounds__(256, 2) void k_fused(
    const float* __restrict__ xg, const float* __restrict__ xtime,
    const __hip_bfloat16* __restrict__ W1t, const float* __restrict__ b1,
    const __hip_bfloat16* __restrict__ W2t, const float* __restrict__ b2,
    const __hip_bfloat16* __restrict__ Wzrt, const float* __restrict__ bz,
    const float* __restrict__ br, const __hip_bfloat16* __restrict__ Wnt,
    const float* __restrict__ bn, float* __restrict__ hf, float* __restrict__ hstdf,
    float* __restrict__ hodef, float* __restrict__ zf,
    __hip_bfloat16* __restrict__ hbf, __hip_bfloat16* __restrict__ Ubf,
    __hip_bfloat16* __restrict__ hodeb, __hip_bfloat16* __restrict__ hstdb,
    __hip_bfloat16* __restrict__ A4, __hip_bfloat16* __restrict__ xstep,
    unsigned* __restrict__ bar) {
  __shared__ __align__(16) unsigned short lA[3][16 * 64];    //  6 KB
  __shared__ __align__(16) unsigned short lB[3][128 * 64];   // 48 KB
  __shared__ __align__(16) float lS0[16 * 128];              //  8 KB
  __shared__ __align__(16) float lS1[16 * 128];              //  8 KB
  int tid = threadIdx.x, lane = tid & 63, wv = tid >> 6;
  int lr = lane & 15, lg = lane >> 4;
  int b = blockIdx.x;
  int xd = b & 7;        // XCD group (round-robin heuristic; perf-only)
  int i = b >> 3;        // 0..63: batch strip index
  int m0 = i << 4;       // 16-row strip, pinned for all phases/steps
  int nA = xd << 6;      // P1/P2 n-slice base (64 cols)
  int nB = xd << 7;      // P3/P4 n-slice base (128 cols)
  unsigned* scnt = bar + i * 32;   // per-strip 128B counter line
  unsigned p = 0;

  // prestage P1 weight tiles 0,1 (L2-resident slice; drained by first sbar)
  stageT<64, 0>(W1t, H_SZ, nA, 0, lB[0], tid);
  stageT<64, 0>(W1t, H_SZ, nA, 64, lB[1], tid);

#pragma unroll 1
  for (int t = 0; t < T_SZ; ++t) {
    sbar(scnt, ++p);  // strip's h/hstd of step t-1 complete
    // ======== P1: U = tanh(h @ W1 + b1), strip x cols [nA,nA+64) ========
    {
      f32x4 acc = {};
      auto sa = [&](int kt, int bi) { stageT<16, AUXS>(hbf, H_SZ, m0, kt << 6, lA[bi], tid); };
      auto sb = [&](int kt, int bi) { stageT<64, 0>(W1t, H_SZ, nA, kt << 6, lB[bi], tid); };
      auto ss = [&]() {};
      auto cc = [&](int bi) {
#pragma unroll
        for (int kk = 0; kk < 2; ++kk) {
          short8 a = ldfrag(lA[bi], lr, (kk << 2) + lg);
          short8 bb = ldfrag(lB[bi], (wv << 4) + lr, (kk << 2) + lg);
          acc = mfma16(a, bb, acc);
        }
      };
      gloop<8, 2, 0>(sa, sb, ss, cc);
      int col = nA + (wv << 4) + lr;
      float bi = b1[col];
#pragma unroll
      for (int r = 0; r < 4; ++r) {
        int rl = (lg << 2) + r;
        st_sys_bf16(&Ubf[(size_t)(m0 + rl) * H_SZ + col], tanhf(acc[r] + bi));
      }
      stageT<64, 0>(W2t, H_SZ, nA, 0, lB[0], tid);   // prestage P2 weights
      stageT<64, 0>(W2t, H_SZ, nA, 64, lB[1], tid);
    }
    sbar(scnt, ++p);
    // ======== P2: h_ode = h + dt*(U @ W2 + b2); x slice -> bf16 ========
    {
      f32x4 acc = {};
      auto sa = [&](int kt, int bi) { stageT<16, AUXS>(Ubf, H_SZ, m0, kt << 6, lA[bi], tid); };
      auto sb = [&](int kt, int bi) { stageT<64, 0>(W2t, H_SZ, nA, kt << 6, lB[bi], tid); };
      auto ss = [&]() { stageF<16, 64>(hf, H_SZ, m0, nA, lS0, tid); };
      auto cc = [&](int bi) {
#pragma unroll
        for (int kk = 0; kk < 2; ++kk) {
          short8 a = ldfrag(lA[bi], lr, (kk << 2) + lg);
          short8 bb = ldfrag(lB[bi], (wv << 4) + lr, (kk << 2) + lg);
          acc = mfma16(a, bb, acc);
        }
      };
      gloop<8, 2, 1>(sa, sb, ss, cc);
      float dtv = (t == 0) ? 0.01f : (xtime[t] - xtime[t - 1]);
      int cl = (wv << 4) + lr;
      int col = nA + cl;
      float bi = b2[col];
#pragma unroll
      for (int r = 0; r < 4; ++r) {
        int rl = (lg << 2) + r;
        float v = lS0[rl * 64 + cl] + dtv * (acc[r] + bi);
        size_t ix = (size_t)(m0 + rl) * H_SZ + col;
        st_sys_f32(&hodef[ix], v);
        st_sys_bf16(&hodeb[ix], v);
      }
      {  // x[:, t, xd-slice] -> bf16 (16 strip rows, 32 cols per XCD-group)
        int colx = (xd << 5) + (tid & 31);
#pragma unroll
        for (int it2 = 0; it2 < 2; ++it2) {
          int row = m0 + (tid >> 5) + (it2 << 3);
          float xv = xg[((size_t)row * T_SZ + t) * D_SZ + colx];
          st_sys_bf16(&xstep[(size_t)row * D_SZ + colx], xv);
        }
      }
      stageT<128, 0>(Wzrt, 1280, nB, 0, lB[0], tid);   // prestage P3
      stageT<128, 0>(Wzrt, 1280, nB, 64, lB[1], tid);
    }
    sbar(scnt, ++p);
    // ======== P3: z|r = sigmoid(cat @ WzrT); strip x 128-col slice ========
    {
      f32x4 acc[2] = {};
      auto sa = [&](int kt, int bi) {
        int ke = kt << 6;
        if (ke < 512)       stageT<16, AUXS>(hodeb, H_SZ, m0, ke, lA[bi], tid);
        else if (ke < 1024) stageT<16, AUXS>(hstdb, H_SZ, m0, ke - 512, lA[bi], tid);
        else                stageT<16, AUXS>(xstep, D_SZ, m0, ke - 1024, lA[bi], tid);
      };
      auto sb = [&](int kt, int bi) { stageT<128, 0>(Wzrt, 1280, nB, kt << 6, lB[bi], tid); };
      auto ss = [&]() {  // r-blocks consume; z-blocks stage (uniform) & ignore
        stageF<16, 128>(hodef, H_SZ, m0, (xd & 3) << 7, lS0, tid);
        stageF<16, 128>(hstdf, H_SZ, m0, (xd & 3) << 7, lS1, tid);
      };
      auto cc = [&](int bi) {
#pragma unroll
        for (int kk = 0; kk < 2; ++kk) {
          short8 a = ldfrag(lA[bi], lr, (kk << 2) + lg);
#pragma unroll
          for (int n = 0; n < 2; ++n) {
            short8 bb = ldfrag(lB[bi], (wv << 5) + (n << 4) + lr, (kk << 2) + lg);
            acc[n] = mfma16(a, bb, acc[n]);
          }
        }
      };
      gloop<20, 4, 4>(sa, sb, ss, cc);
      if (xd < 4) {  // z columns [xd*128, +128)
#pragma unroll
        for (int n = 0; n < 2; ++n) {
          int cl = (wv << 5) + (n << 4) + lr;
          int cg = nB + cl;
          float bi = bz[cg];
#pragma unroll
          for (int r = 0; r < 4; ++r) {
            int rl = (lg << 2) + r;
            float g = 1.f / (1.f + expf(-(acc[n][r] + bi)));
            st_sys_f32(&zf[(size_t)(m0 + rl) * H_SZ + cg], g);
          }
        }
      } else {  // r columns -> A4 = [h_ode*r | hstd*r]
#pragma unroll
        for (int n = 0; n < 2; ++n) {
          int cl = (wv << 5) + (n << 4) + lr;
          int j = ((xd & 3) << 7) + cl;
          float bi = br[j];
#pragma unroll
          for (int r = 0; r < 4; ++r) {
            int rl = (lg << 2) + r;
            int row = m0 + rl;
            float g = 1.f / (1.f + expf(-(acc[n][r] + bi)));
            st_sys_bf16(&A4[(size_t)row * 1024 + j], lS0[rl * 128 + cl] * g);
            st_sys_bf16(&A4[(size_t)row * 1024 + 512 + j], lS1[rl * 128 + cl] * g);
          }
        }
      }
      stageT<128, 0>(Wnt, 1280, nB, 0, lB[0], tid);   // prestage P4
      stageT<128, 0>(Wnt, 1280, nB, 64, lB[1], tid);
    }
    sbar(scnt, ++p);
    // ======== P4: n = cat_r @ Wn + bn; GRU update; strip x 128-col slice ====
    {
      f32x4 acc[2] = {};
      auto sa = [&](int kt, int bi) {
        int ke = kt << 6;
        if (ke < 1024) stageT<16, AUXS>(A4, 1024, m0, ke, lA[bi], tid);
        else           stageT<16, AUXS>(xstep, D_SZ, m0, ke - 1024, lA[bi], tid);
      };
      auto sb = [&](int kt, int bi) { stageT<128, 0>(Wnt, 1280, nB, kt << 6, lB[bi], tid); };
      const float* s1src = (xd < 4) ? hodef : hstdf;
      auto ss = [&]() {
        stageF<16, 128>(zf, H_SZ, m0, (xd & 3) << 7, lS0, tid);
        stageF<16, 128>(s1src, H_SZ, m0, (xd & 3) << 7, lS1, tid);
      };
      auto cc = [&](int bi) {
#pragma unroll
        for (int kk = 0; kk < 2; ++kk) {
          short8 a = ldfrag(lA[bi], lr, (kk << 2) + lg);
#pragma unroll
          for (int n = 0; n < 2; ++n) {
            short8 bb = ldfrag(lB[bi], (wv << 5) + (n << 4) + lr, (kk << 2) + lg);
            acc[n] = mfma16(a, bb, acc[n]);
          }
        }
      };
      gloop<20, 4, 4>(sa, sb, ss, cc);
      if (xd < 4) {  // mean columns -> h update
#pragma unroll
        for (int n = 0; n < 2; ++n) {
          int cl = (wv << 5) + (n << 4) + lr;
          int c = nB + cl;
          float bi = bn[c];
#pragma unroll
          for (int r = 0; r < 4; ++r) {
            int rl = (lg << 2) + r;
            size_t ix = (size_t)(m0 + rl) * H_SZ + c;
            float nm = acc[n][r] + bi;
            float z = lS0[rl * 128 + cl], ho = lS1[rl * 128 + cl];
            float hn = (1.f - z) * nm + z * ho;
            st_sys_f32(&hf[ix], hn);
            st_sys_bf16(&hbf[ix], hn);
          }
        }
      } else {  // std columns -> hstd update
#pragma unroll
        for (int n = 0; n < 2; ++n) {
          int cl = (wv << 5) + (n << 4) + lr;
          int j = ((xd & 3) << 7) + cl;
          float bi = bn[512 + j];
#pragma unroll
          for (int r = 0; r < 4; ++r) {
            int rl = (lg << 2) + r;
            size_t ix = (size_t)(m0 + rl) * H_SZ + j;
            float ns = fabsf(acc[n][r] + bi);
            float z = lS0[rl * 128 + cl], hs = lS1[rl * 128 + cl];
            float sn = fabsf((1.f - z) * ns + z * hs);
            st_sys_f32(&hstdf[ix], sn);
            st_sys_bf16(&hstdb[ix], sn);
          }
        }
      }
      stageT<64, 0>(W1t, H_SZ, nA, 0, lB[0], tid);   // prestage next-step P1
      stageT<64, 0>(W1t, H_SZ, nA, 64, lB[1], tid);
    }
  }
}

// =============== prep: W[k][n] f32  ->  Wt[n][k] bf16 =====================
__global__ void k_wt(const float* __restrict__ W, __hip_bfloat16* __restrict__ Wt,
                     int K, int N, int ld) {
  size_t i = (size_t)blockIdx.x * 256 + threadIdx.x;
  if (i >= (size_t)K * N) return;
  int n = (int)(i / K), k = (int)(i % K);
  Wt[(size_t)n * ld + k] = __float2bfloat16(W[(size_t)k * N + n]);
}

extern "C" void kernel_launch(void* const* d_in, const int* in_sizes, int n_in,
                              void* d_out, int out_size, void* d_ws, size_t ws_size,
                              hipStream_t stream) {
  const float* x     = (const float*)d_in[0];
  const float* xtime = (const float*)d_in[1];
  const float* W1    = (const float*)d_in[2];
  const float* b1    = (const float*)d_in[3];
  const float* W2    = (const float*)d_in[4];
  const float* b2    = (const float*)d_in[5];
  const float* Wz    = (const float*)d_in[6];
  const float* bz    = (const float*)d_in[7];
  const float* Wr    = (const float*)d_in[8];
  const float* br    = (const float*)d_in[9];
  const float* Wn    = (const float*)d_in[10];
  const float* bn    = (const float*)d_in[11];

  char* p = (char*)d_ws;
  __hip_bfloat16* W1t   = (__hip_bfloat16*)(p + 0);
  __hip_bfloat16* W2t   = (__hip_bfloat16*)(p + 524288);
  __hip_bfloat16* Wzrt  = (__hip_bfloat16*)(p + 1048576);
  __hip_bfloat16* Wnt   = (__hip_bfloat16*)(p + 3670016);
  float*          hf    = (float*)(p + 6291456);
  float*          hstdf = (float*)(p + 8388608);
  float*          hodef = (float*)(p + 10485760);
  float*          zf    = (float*)(p + 12582912);
  __hip_bfloat16* hbf   = (__hip_bfloat16*)(p + 14680064);
  __hip_bfloat16* Ubf   = (__hip_bfloat16*)(p + 15728640);
  __hip_bfloat16* hodeb = (__hip_bfloat16*)(p + 16777216);
  __hip_bfloat16* hstdb = (__hip_bfloat16*)(p + 17825792);
  __hip_bfloat16* A4    = (__hip_bfloat16*)(p + 18874368);
  __hip_bfloat16* xstep = (__hip_bfloat16*)(p + 20971520);
  unsigned*       bar   = (unsigned*)(p + 21495808);

  hipMemsetAsync(hf, 0, 2097152, stream);
  hipMemsetAsync(hstdf, 0, 2097152, stream);
  hipMemsetAsync(hbf, 0, 1048576, stream);
  hipMemsetAsync(hstdb, 0, 1048576, stream);
  hipMemsetAsync(bar, 0, 8192, stream);

  k_wt<<<(512 * 512 + 255) / 256, 256, 0, stream>>>(W1, W1t, 512, 512, 512);
  k_wt<<<(512 * 512 + 255) / 256, 256, 0, stream>>>(W2, W2t, 512, 512, 512);
  k_wt<<<(1280 * 512 + 255) / 256, 256, 0, stream>>>(Wz, Wzrt, 1280, 512, 1280);
  k_wt<<<(1280 * 512 + 255) / 256, 256, 0, stream>>>(Wr, Wzrt + (size_t)512 * 1280, 1280, 512, 1280);
  k_wt<<<(1280 * 1024 + 255) / 256, 256, 0, stream>>>(Wn, Wnt, 1280, 1024, 1280);

  // persistent kernel: 64 strips x 8 n-slice blocks, 2 blocks/CU (2 waves/SIMD)
  k_fused<<<NBLK, 256, 0, stream>>>(x, xtime, W1t, b1, W2t, b2, Wzrt, bz, br,
                                    Wnt, bn, hf, hstdf, hodef, zf, hbf, Ubf,
                                    hodeb, hstdb, A4, xstep, bar);

  hipMemcpyAsync(d_out, hf, 2097152, hipMemcpyDeviceToDevice, stream);
  hipMemcpyAsync((char*)d_out + 2097152, hstdf, 2097152, hipMemcpyDeviceToDevice, stream);
}

// Round 9
// 6852.484 us; speedup vs baseline: 3.4842x; 1.0374x over previous
//
#include <hip/hip_runtime.h>
#include <hip/hip_bf16.h>

#define B_SZ 1024
#define T_SZ 128
#define D_SZ 256
#define H_SZ 512
#define NBLK 512
#define AUXS 0x11   // CPol SC0|SC1: system-coherent, bypass L1/L2 (state path)

typedef __attribute__((ext_vector_type(8))) short short8;
typedef __attribute__((ext_vector_type(4))) float f32x4;

__device__ inline f32x4 mfma16(short8 a, short8 b, f32x4 c) {
  return __builtin_amdgcn_mfma_f32_16x16x32_bf16(a, b, c, 0, 0, 0);
}

__device__ inline void st_sys_bf16(__hip_bfloat16* p, float v) {
  union { __hip_bfloat16 b; unsigned short u; } cv;
  cv.b = __float2bfloat16(v);
  unsigned int vv = cv.u;
  asm volatile("global_store_short %0, %1, off sc0 sc1" :: "v"(p), "v"(vv) : "memory");
}

// Stage ROWSx64 bf16 tile -> LDS [ROWS][64], slot-swizzled (slot s of row r
// holds k-slot s^(r&7)); linear LDS dest + inverse-swizzled global source.
// Wave-uniform guard: for ROWS=16 only waves 0,1 issue (barrier propagates
// their vmcnt guarantee to the non-issuing waves).
template <int ROWS, int AUX>
__device__ __forceinline__ void stageT(const __hip_bfloat16* __restrict__ src,
                                       int strideElts, int row0, int k0,
                                       unsigned short* lds, int tid) {
  constexpr int CH = ROWS * 8;
#pragma unroll
  for (int it = 0; it * 256 < CH; ++it) {
    int wbase = it * 256 + ((tid >> 6) << 6);
    if (wbase < CH) {
      int chunk = it * 256 + tid;
      int row = chunk >> 3, slot = chunk & 7;
      int ksrc = (slot ^ (row & 7)) << 3;
      const __hip_bfloat16* g = src + (size_t)(row0 + row) * strideElts + (k0 + ksrc);
      unsigned short* l = lds + (size_t)wbase * 8;
      __builtin_amdgcn_global_load_lds(
          (const __attribute__((address_space(1))) unsigned int*)g,
          (__attribute__((address_space(3))) unsigned int*)l, 16, 0, AUX);
    }
  }
}

__device__ __forceinline__ short8 ldfrag(const unsigned short* lds, int row, int slot) {
  int s = slot ^ (row & 7);
  return *(const short8*)(lds + row * 64 + s * 8);
}

// Counted-vmcnt mainloop: A-depth 4 (6 buffers), B-depth 2 (3 buffers).
// B tiles 0,1 prestaged before the strip barrier (its vmcnt(0) drains them).
// Wait derivation (per issuing wave, in-order counter, A issued before B in
// each iter): kt=0: outstanding A0..A3 -> vmcnt(3) forces A0. kt=1: A1..A4 +
// B2 -> vmcnt(3+PB) forces A1 (B1 pre-drained). kt>=2: younger-than-B[kt] =
// A[kt+3] + B[kt+1] = 1+PB -> vmcnt(1+PB) forces B[kt] and A[<=kt+2].
// Non-issuing waves inherit through s_barrier.
template <int NT, int PB, typename SA, typename SB, typename CC>
__device__ __forceinline__ void gloop(SA sa, SB sb, CC cc) {
  sa(0, 0); sa(1, 1); sa(2, 2); sa(3, 3);
#pragma unroll 1
  for (int kt = 0; kt < NT; ++kt) {
    if (kt == 0)
      asm volatile("s_waitcnt vmcnt(3)" ::: "memory");
    else if (kt == 1)
      asm volatile("s_waitcnt vmcnt(%0)" :: "i"(3 + PB) : "memory");
    else if (kt < NT - 1)
      asm volatile("s_waitcnt vmcnt(%0)" :: "i"(1 + PB) : "memory");
    else
      asm volatile("s_waitcnt vmcnt(0)" ::: "memory");
    __builtin_amdgcn_s_barrier();
    __builtin_amdgcn_sched_barrier(0);
    if (kt + 4 < NT) sa(kt + 4, (kt + 4) % 6);
    if (kt + 2 < NT) sb(kt + 2, (kt + 2) % 3);
    cc(kt % 6, kt % 3);
  }
}

// Strip-local 8-block barrier: monotonic counter, relaxed atomics, no fences.
__device__ __forceinline__ void sbar(unsigned* scnt, unsigned p) {
  asm volatile("s_waitcnt vmcnt(0)" ::: "memory");  // all waves drain sc-stores
  __syncthreads();
  if (threadIdx.x == 0) {
    __hip_atomic_fetch_add(scnt, 1u, __ATOMIC_RELAXED, __HIP_MEMORY_SCOPE_AGENT);
    while (__hip_atomic_load(scnt, __ATOMIC_RELAXED, __HIP_MEMORY_SCOPE_AGENT) < p * 8u)
      __builtin_amdgcn_s_sleep(1);
  }
  __syncthreads();
  __builtin_amdgcn_sched_barrier(0);
}

__global__ __launch_bounds__(256, 2) void k_fused(
    const float* __restrict__ xg, const float* __restrict__ xtime,
    const __hip_bfloat16* __restrict__ W1t, const float* __restrict__ b1,
    const __hip_bfloat16* __restrict__ W2t, const float* __restrict__ b2,
    const __hip_bfloat16* __restrict__ Wzrt, const float* __restrict__ bz,
    const float* __restrict__ br, const __hip_bfloat16* __restrict__ Wnt,
    const float* __restrict__ bn, float* __restrict__ hf, float* __restrict__ hstdf,
    __hip_bfloat16* __restrict__ hbf, __hip_bfloat16* __restrict__ Ubf,
    __hip_bfloat16* __restrict__ hodeb, __hip_bfloat16* __restrict__ hstdb,
    __hip_bfloat16* __restrict__ A4, __hip_bfloat16* __restrict__ xstep,
    unsigned* __restrict__ bar) {
  __shared__ __align__(16) unsigned short lA[6][16 * 64];    // 12 KB (A depth-4)
  __shared__ __align__(16) unsigned short lB[3][128 * 64];   // 48 KB
  // block-private f32 state for the owned 64 columns (never leaves LDS)
  __shared__ __align__(16) float hloc[16 * 64];              // 4 KB
  __shared__ __align__(16) float hstdloc[16 * 64];           // 4 KB
  __shared__ __align__(16) float hodeloc[16 * 64];           // 4 KB
  __shared__ __align__(16) float zloc[16 * 64];              // 4 KB
  int tid = threadIdx.x, lane = tid & 63, wv = tid >> 6;
  int lr = lane & 15, lg = lane >> 4;
  int b = blockIdx.x;
  int s = b & 7;         // column-slice owner (also XCD heuristic; perf-only)
  int i = b >> 3;        // 0..63: batch strip index
  int m0 = i << 4;       // 16-row strip
  int nA = s << 6;       // owned 64-column base (all phases)
  unsigned* scnt = bar + i * 32;
  unsigned p = 0;

  // zero private state (h0 = std0 = 0); visible to all waves via first sbar
  for (int idx = tid; idx < 16 * 64; idx += 256) { hloc[idx] = 0.f; hstdloc[idx] = 0.f; }

  // prestage P1 weight tiles 0,1
  stageT<64, 0>(W1t, H_SZ, nA, 0, lB[0], tid);
  stageT<64, 0>(W1t, H_SZ, nA, 64, lB[1], tid);

#pragma unroll 1
  for (int t = 0; t < T_SZ; ++t) {
    sbar(scnt, ++p);  // strip's hbf/hstdb of step t-1 complete
    // ======== P1: U = tanh(h @ W1 + b1), owned cols ========
    {
      f32x4 acc = {};
      auto sa = [&](int kt, int bi) { stageT<16, AUXS>(hbf, H_SZ, m0, kt << 6, lA[bi], tid); };
      auto sb = [&](int kt, int bi) { stageT<64, 0>(W1t, H_SZ, nA, kt << 6, lB[bi], tid); };
      auto cc = [&](int ai, int bi) {
#pragma unroll
        for (int kk = 0; kk < 2; ++kk) {
          short8 a = ldfrag(lA[ai], lr, (kk << 2) + lg);
          short8 bb = ldfrag(lB[bi], (wv << 4) + lr, (kk << 2) + lg);
          acc = mfma16(a, bb, acc);
        }
      };
      gloop<8, 2>(sa, sb, cc);
      int col = nA + (wv << 4) + lr;
      float bi = b1[col];
#pragma unroll
      for (int r = 0; r < 4; ++r) {
        int rl = (lg << 2) + r;
        st_sys_bf16(&Ubf[(size_t)(m0 + rl) * H_SZ + col], tanhf(acc[r] + bi));
      }
      stageT<64, 0>(W2t, H_SZ, nA, 0, lB[0], tid);   // prestage P2 weights
      stageT<64, 0>(W2t, H_SZ, nA, 64, lB[1], tid);
    }
    sbar(scnt, ++p);
    // ======== P2: h_ode = h + dt*(U @ W2 + b2); x slice -> bf16 ========
    {
      f32x4 acc = {};
      auto sa = [&](int kt, int bi) { stageT<16, AUXS>(Ubf, H_SZ, m0, kt << 6, lA[bi], tid); };
      auto sb = [&](int kt, int bi) { stageT<64, 0>(W2t, H_SZ, nA, kt << 6, lB[bi], tid); };
      auto cc = [&](int ai, int bi) {
#pragma unroll
        for (int kk = 0; kk < 2; ++kk) {
          short8 a = ldfrag(lA[ai], lr, (kk << 2) + lg);
          short8 bb = ldfrag(lB[bi], (wv << 4) + lr, (kk << 2) + lg);
          acc = mfma16(a, bb, acc);
        }
      };
      gloop<8, 2>(sa, sb, cc);
      float dtv = (t == 0) ? 0.01f : (xtime[t] - xtime[t - 1]);
      int cl = (wv << 4) + lr;
      int col = nA + cl;
      float bi = b2[col];
#pragma unroll
      for (int r = 0; r < 4; ++r) {
        int rl = (lg << 2) + r;
        float v = hloc[rl * 64 + cl] + dtv * (acc[r] + bi);
        hodeloc[rl * 64 + cl] = v;
        st_sys_bf16(&hodeb[(size_t)(m0 + rl) * H_SZ + col], v);
      }
      {  // x[:, t, s-slice] -> bf16 (16 strip rows, 32 cols per slice)
        int colx = (s << 5) + (tid & 31);
#pragma unroll
        for (int it2 = 0; it2 < 2; ++it2) {
          int row = m0 + (tid >> 5) + (it2 << 3);
          float xv = xg[((size_t)row * T_SZ + t) * D_SZ + colx];
          st_sys_bf16(&xstep[(size_t)row * D_SZ + colx], xv);
        }
      }
      // prestage P3 weights: [z-rows | r-rows] halves of lB
      stageT<64, 0>(Wzrt, 1280, nA, 0, lB[0], tid);
      stageT<64, 0>(Wzrt, 1280, 512 + nA, 0, lB[0] + 64 * 64, tid);
      stageT<64, 0>(Wzrt, 1280, nA, 64, lB[1], tid);
      stageT<64, 0>(Wzrt, 1280, 512 + nA, 64, lB[1] + 64 * 64, tid);
    }
    sbar(scnt, ++p);
    // ======== P3: z,r = sigmoid(cat @ WzrT) for owned cols; build A4 ========
    {
      f32x4 acc[2] = {};
      auto sa = [&](int kt, int bi) {
        int ke = kt << 6;
        if (ke < 512)       stageT<16, AUXS>(hodeb, H_SZ, m0, ke, lA[bi], tid);
        else if (ke < 1024) stageT<16, AUXS>(hstdb, H_SZ, m0, ke - 512, lA[bi], tid);
        else                stageT<16, AUXS>(xstep, D_SZ, m0, ke - 1024, lA[bi], tid);
      };
      auto sb = [&](int kt, int bi) {
        stageT<64, 0>(Wzrt, 1280, nA, kt << 6, lB[bi], tid);
        stageT<64, 0>(Wzrt, 1280, 512 + nA, kt << 6, lB[bi] + 64 * 64, tid);
      };
      auto cc = [&](int ai, int bi) {
#pragma unroll
        for (int kk = 0; kk < 2; ++kk) {
          short8 a = ldfrag(lA[ai], lr, (kk << 2) + lg);
#pragma unroll
          for (int n = 0; n < 2; ++n) {
            short8 bb = ldfrag(lB[bi], (wv << 5) + (n << 4) + lr, (kk << 2) + lg);
            acc[n] = mfma16(a, bb, acc[n]);
          }
        }
      };
      gloop<20, 4>(sa, sb, cc);
      if (wv < 2) {  // z: local rows 0..63 of lB -> zloc
#pragma unroll
        for (int n = 0; n < 2; ++n) {
          int cl = (wv << 5) + (n << 4) + lr;   // 0..63
          float bi = bz[nA + cl];
#pragma unroll
          for (int r = 0; r < 4; ++r) {
            int rl = (lg << 2) + r;
            zloc[rl * 64 + cl] = 1.f / (1.f + expf(-(acc[n][r] + bi)));
          }
        }
      } else {  // r: local rows 64..127 -> A4 = [h_ode*r | hstd*r] (sc, K-dim)
#pragma unroll
        for (int n = 0; n < 2; ++n) {
          int cl = ((wv - 2) << 5) + (n << 4) + lr;  // 0..63
          int j = nA + cl;
          float bi = br[j];
#pragma unroll
          for (int r = 0; r < 4; ++r) {
            int rl = (lg << 2) + r;
            int row = m0 + rl;
            float g = 1.f / (1.f + expf(-(acc[n][r] + bi)));
            st_sys_bf16(&A4[(size_t)row * 1024 + j], hodeloc[rl * 64 + cl] * g);
            st_sys_bf16(&A4[(size_t)row * 1024 + 512 + j], hstdloc[rl * 64 + cl] * g);
          }
        }
      }
      // prestage P4 weights: [mean-rows | std-rows]
      stageT<64, 0>(Wnt, 1280, nA, 0, lB[0], tid);
      stageT<64, 0>(Wnt, 1280, 512 + nA, 0, lB[0] + 64 * 64, tid);
      stageT<64, 0>(Wnt, 1280, nA, 64, lB[1], tid);
      stageT<64, 0>(Wnt, 1280, 512 + nA, 64, lB[1] + 64 * 64, tid);
    }
    sbar(scnt, ++p);
    // ======== P4: n_mean,n_std for owned cols; GRU update in LDS ========
    {
      f32x4 acc[2] = {};
      auto sa = [&](int kt, int bi) {
        int ke = kt << 6;
        if (ke < 1024) stageT<16, AUXS>(A4, 1024, m0, ke, lA[bi], tid);
        else           stageT<16, AUXS>(xstep, D_SZ, m0, ke - 1024, lA[bi], tid);
      };
      auto sb = [&](int kt, int bi) {
        stageT<64, 0>(Wnt, 1280, nA, kt << 6, lB[bi], tid);
        stageT<64, 0>(Wnt, 1280, 512 + nA, kt << 6, lB[bi] + 64 * 64, tid);
      };
      auto cc = [&](int ai, int bi) {
#pragma unroll
        for (int kk = 0; kk < 2; ++kk) {
          short8 a = ldfrag(lA[ai], lr, (kk << 2) + lg);
#pragma unroll
          for (int n = 0; n < 2; ++n) {
            short8 bb = ldfrag(lB[bi], (wv << 5) + (n << 4) + lr, (kk << 2) + lg);
            acc[n] = mfma16(a, bb, acc[n]);
          }
        }
      };
      gloop<20, 4>(sa, sb, cc);
      if (wv < 2) {  // mean cols -> h update (hloc + hbf)
#pragma unroll
        for (int n = 0; n < 2; ++n) {
          int cl = (wv << 5) + (n << 4) + lr;
          int c = nA + cl;
          float bi = bn[c];
#pragma unroll
          for (int r = 0; r < 4; ++r) {
            int rl = (lg << 2) + r;
            float nm = acc[n][r] + bi;
            float z = zloc[rl * 64 + cl], ho = hodeloc[rl * 64 + cl];
            float hn = (1.f - z) * nm + z * ho;
            hloc[rl * 64 + cl] = hn;
            st_sys_bf16(&hbf[(size_t)(m0 + rl) * H_SZ + c], hn);
          }
        }
      } else {  // std cols -> hstd update (hstdloc + hstdb)
#pragma unroll
        for (int n = 0; n < 2; ++n) {
          int cl = ((wv - 2) << 5) + (n << 4) + lr;
          int j = nA + cl;
          float bi = bn[512 + j];
#pragma unroll
          for (int r = 0; r < 4; ++r) {
            int rl = (lg << 2) + r;
            float ns = fabsf(acc[n][r] + bi);
            float z = zloc[rl * 64 + cl], hs = hstdloc[rl * 64 + cl];
            float sn = fabsf((1.f - z) * ns + z * hs);
            hstdloc[rl * 64 + cl] = sn;
            st_sys_bf16(&hstdb[(size_t)(m0 + rl) * H_SZ + j], sn);
          }
        }
      }
      stageT<64, 0>(W1t, H_SZ, nA, 0, lB[0], tid);   // prestage next-step P1
      stageT<64, 0>(W1t, H_SZ, nA, 64, lB[1], tid);
    }
  }
  // final output: private f32 state -> global (kernel-end flush covers memcpy)
  __syncthreads();
  for (int idx = tid; idx < 16 * 64; idx += 256) {
    int rl = idx >> 6, cl = idx & 63;
    hf[(size_t)(m0 + rl) * H_SZ + nA + cl] = hloc[idx];
    hstdf[(size_t)(m0 + rl) * H_SZ + nA + cl] = hstdloc[idx];
  }
}

// =============== prep: W[k][n] f32  ->  Wt[n][k] bf16 =====================
__global__ void k_wt(const float* __restrict__ W, __hip_bfloat16* __restrict__ Wt,
                     int K, int N, int ld) {
  size_t i = (size_t)blockIdx.x * 256 + threadIdx.x;
  if (i >= (size_t)K * N) return;
  int n = (int)(i / K), k = (int)(i % K);
  Wt[(size_t)n * ld + k] = __float2bfloat16(W[(size_t)k * N + n]);
}

extern "C" void kernel_launch(void* const* d_in, const int* in_sizes, int n_in,
                              void* d_out, int out_size, void* d_ws, size_t ws_size,
                              hipStream_t stream) {
  const float* x     = (const float*)d_in[0];
  const float* xtime = (const float*)d_in[1];
  const float* W1    = (const float*)d_in[2];
  const float* b1    = (const float*)d_in[3];
  const float* W2    = (const float*)d_in[4];
  const float* b2    = (const float*)d_in[5];
  const float* Wz    = (const float*)d_in[6];
  const float* bz    = (const float*)d_in[7];
  const float* Wr    = (const float*)d_in[8];
  const float* br    = (const float*)d_in[9];
  const float* Wn    = (const float*)d_in[10];
  const float* bn    = (const float*)d_in[11];

  char* p = (char*)d_ws;
  __hip_bfloat16* W1t   = (__hip_bfloat16*)(p + 0);
  __hip_bfloat16* W2t   = (__hip_bfloat16*)(p + 524288);
  __hip_bfloat16* Wzrt  = (__hip_bfloat16*)(p + 1048576);
  __hip_bfloat16* Wnt   = (__hip_bfloat16*)(p + 3670016);
  float*          hf    = (float*)(p + 6291456);
  float*          hstdf = (float*)(p + 8388608);
  __hip_bfloat16* hbf   = (__hip_bfloat16*)(p + 14680064);
  __hip_bfloat16* Ubf   = (__hip_bfloat16*)(p + 15728640);
  __hip_bfloat16* hodeb = (__hip_bfloat16*)(p + 16777216);
  __hip_bfloat16* hstdb = (__hip_bfloat16*)(p + 17825792);
  __hip_bfloat16* A4    = (__hip_bfloat16*)(p + 18874368);
  __hip_bfloat16* xstep = (__hip_bfloat16*)(p + 20971520);
  unsigned*       bar   = (unsigned*)(p + 21495808);

  hipMemsetAsync(hbf, 0, 1048576, stream);
  hipMemsetAsync(hstdb, 0, 1048576, stream);
  hipMemsetAsync(bar, 0, 8192, stream);

  k_wt<<<(512 * 512 + 255) / 256, 256, 0, stream>>>(W1, W1t, 512, 512, 512);
  k_wt<<<(512 * 512 + 255) / 256, 256, 0, stream>>>(W2, W2t, 512, 512, 512);
  k_wt<<<(1280 * 512 + 255) / 256, 256, 0, stream>>>(Wz, Wzrt, 1280, 512, 1280);
  k_wt<<<(1280 * 512 + 255) / 256, 256, 0, stream>>>(Wr, Wzrt + (size_t)512 * 1280, 1280, 512, 1280);
  k_wt<<<(1280 * 1024 + 255) / 256, 256, 0, stream>>>(Wn, Wnt, 1280, 1024, 1280);

  // persistent kernel: 64 strips x 8 column-slice blocks; per-slice f32 state
  // lives in LDS; only bf16 K-dim operands cross blocks (sc0/sc1 path)
  k_fused<<<NBLK, 256, 0, stream>>>(x, xtime, W1t, b1, W2t, b2, Wzrt, bz, br,
                                    Wnt, bn, hf, hstdf, hbf, Ubf,
                                    hodeb, hstdb, A4, xstep, bar);

  hipMemcpyAsync(d_out, hf, 2097152, hipMemcpyDeviceToDevice, stream);
  hipMemcpyAsync((char*)d_out + 2097152, hstdf, 2097152, hipMemcpyDeviceToDevice, stream);
}